// Round 2
// baseline (1289.381 us; speedup 1.0000x reference)
//
#include <hip/hip_runtime.h>
#include <hip/hip_bf16.h>

typedef __hip_bfloat16 bf16;

#define B_ 8
#define T_ 1024
#define D_ 1024
#define N_ 256
#define L_ 768
#define H_ 16
#define HD_ 64
#define TE_ 2048

__device__ __forceinline__ float bitf(unsigned u) { return __uint_as_float(u); }

__device__ __forceinline__ float tof(float x) { return x; }
__device__ __forceinline__ float tof(bf16 x)  { return __bfloat162float(x); }
__device__ __forceinline__ void stor(float* p, float v) { *p = v; }
__device__ __forceinline__ void stor(bf16* p, float v)  { *p = __float2bfloat16(v); }

__device__ __forceinline__ void unpack8(uint4 u, float* f) {
    f[0] = bitf(u.x << 16); f[1] = bitf(u.x & 0xffff0000u);
    f[2] = bitf(u.y << 16); f[3] = bitf(u.y & 0xffff0000u);
    f[4] = bitf(u.z << 16); f[5] = bitf(u.z & 0xffff0000u);
    f[6] = bitf(u.w << 16); f[7] = bitf(u.w & 0xffff0000u);
}

// ---------------- LayerNorm: one block (256 thr) per row; f32 in, bf16 out
__global__ __launch_bounds__(256) void ln_kernel(const float* __restrict__ in,
                                                 const float* __restrict__ g,
                                                 const float* __restrict__ bb,
                                                 bf16* __restrict__ out, int cols) {
    int row = blockIdx.x;
    const float* rp = in + (size_t)row * cols;
    float s = 0.f, s2 = 0.f;
    for (int i = threadIdx.x; i < cols; i += 256) {
        float v = rp[i]; s += v; s2 += v * v;
    }
    for (int off = 32; off; off >>= 1) {
        s  += __shfl_down(s,  off, 64);
        s2 += __shfl_down(s2, off, 64);
    }
    __shared__ float ps[4], ps2[4];
    __shared__ float smu, srstd;
    int wid = threadIdx.x >> 6, lid = threadIdx.x & 63;
    if (lid == 0) { ps[wid] = s; ps2[wid] = s2; }
    __syncthreads();
    if (threadIdx.x == 0) {
        float t = ps[0] + ps[1] + ps[2] + ps[3];
        float t2 = ps2[0] + ps2[1] + ps2[2] + ps2[3];
        float m = t / cols;
        float var = t2 / cols - m * m;
        smu = m; srstd = rsqrtf(var + 1e-5f);
    }
    __syncthreads();
    float mu = smu, rstd = srstd;
    for (int i = threadIdx.x; i < cols; i += 256) {
        float v = rp[i];
        float o = (v - mu) * rstd * g[i] + bb[i];
        out[(size_t)row * cols + i] = __float2bfloat16(o);
    }
}

// ------- Tiled GEMM: C = A(MxK) @ W(KxN) + bias [+ res]; W/bias/res f32 ---
template <bool RES, typename TA, typename TC>
__global__ __launch_bounds__(256) void gemm_kernel(const TA* __restrict__ A,
                                                   const float* __restrict__ W,
                                                   const float* __restrict__ bias,
                                                   const float* __restrict__ res,
                                                   TC* __restrict__ C,
                                                   int M, int Nc, int K) {
    __shared__ float As[16][65];
    __shared__ float Ws[16][65];
    int tid = threadIdx.x;
    int tx = tid & 15, ty = tid >> 4;
    int m0 = blockIdx.y * 64, n0 = blockIdx.x * 64;
    float acc[4][4] = {};
    for (int kt = 0; kt < K; kt += 16) {
#pragma unroll
        for (int e = 0; e < 4; e++) {
            int li = tid + 256 * e;
            int m = li >> 4, kk = li & 15;
            As[kk][m] = tof(A[(size_t)(m0 + m) * K + kt + kk]);
        }
#pragma unroll
        for (int e = 0; e < 4; e++) {
            int li = tid + 256 * e;
            int kk = li >> 6, nn = li & 63;
            Ws[kk][nn] = W[(size_t)(kt + kk) * Nc + n0 + nn];
        }
        __syncthreads();
#pragma unroll
        for (int k = 0; k < 16; k++) {
            float a[4], b[4];
#pragma unroll
            for (int i = 0; i < 4; i++) a[i] = As[k][ty + 16 * i];
#pragma unroll
            for (int j = 0; j < 4; j++) b[j] = Ws[k][tx + 16 * j];
#pragma unroll
            for (int i = 0; i < 4; i++)
#pragma unroll
                for (int j = 0; j < 4; j++) acc[i][j] += a[i] * b[j];
        }
        __syncthreads();
    }
#pragma unroll
    for (int i = 0; i < 4; i++) {
        int m = m0 + ty + 16 * i;
#pragma unroll
        for (int j = 0; j < 4; j++) {
            int n = n0 + tx + 16 * j;
            float v = acc[i][j] + bias[n];
            if (RES) v += res[(size_t)m * Nc + n];
            stor(&C[(size_t)m * Nc + n], v);
        }
    }
}

// ---------------- silu(emb) @ Wemb + bemb  (M=8, tiny); all f32 ----------
__global__ __launch_bounds__(256) void emb_kernel(const float* __restrict__ emb,
                                                  const float* __restrict__ Wemb,
                                                  const float* __restrict__ bemb,
                                                  float* __restrict__ embo) {
    int idx = blockIdx.x * 256 + threadIdx.x;
    int b = idx >> 11;       // / 2048
    int j = idx & 2047;
    __shared__ float se[TE_];
    for (int e = threadIdx.x; e < TE_; e += 256) {
        float x = emb[b * TE_ + e];
        se[e] = x / (1.f + __expf(-x));
    }
    __syncthreads();
    float acc = 0.f;
    for (int e = 0; e < TE_; e++)
        acc += se[e] * Wemb[(size_t)e * 2048 + j];
    embo[idx] = acc + bemb[j];
}

// ---------------- attention: block = (b,h, t-chunk of 256); bf16 in/out --
__global__ __launch_bounds__(256) void attn_kernel(const bf16* __restrict__ q,
                                                   const bf16* __restrict__ k,
                                                   const bf16* __restrict__ v,
                                                   bf16* __restrict__ y) {
    __shared__ __align__(16) unsigned short Ksh[N_ * HD_];
    __shared__ __align__(16) unsigned short Vsh[N_ * HD_];
    int bh = blockIdx.x;
    int b = bh >> 4, h = bh & 15;
    int t = blockIdx.y * 256 + threadIdx.x;

    const unsigned short* kp = (const unsigned short*)k;
    const unsigned short* vp = (const unsigned short*)v;
    for (int c = threadIdx.x; c < (N_ * HD_ / 8); c += 256) {   // 2048 uint4 chunks
        int n = c >> 3;
        int d8 = (c & 7) * 8;
        size_t gidx = ((size_t)(b * N_ + n) * D_) + h * HD_ + d8;
        *((uint4*)&Ksh[n * HD_ + d8]) = *((const uint4*)&kp[gidx]);
        *((uint4*)&Vsh[n * HD_ + d8]) = *((const uint4*)&vp[gidx]);
    }
    __syncthreads();

    float qf[64];
    {
        const unsigned short* qp = (const unsigned short*)q + ((size_t)(b * T_ + t) * D_) + h * HD_;
#pragma unroll
        for (int c = 0; c < 8; c++) {
            uint4 u = *((const uint4*)&qp[c * 8]);
            unpack8(u, &qf[c * 8]);
        }
    }
    const float scale = 0.125f;  // 1/sqrt(64)

    // pass 1: running max of scaled scores
    float mmax = -1e30f;
    for (int n = 0; n < N_; n++) {
        float s = 0.f;
#pragma unroll
        for (int c = 0; c < 8; c++) {
            uint4 u = *((uint4*)&Ksh[n * HD_ + c * 8]);
            float kf[8]; unpack8(u, kf);
#pragma unroll
            for (int j = 0; j < 8; j++) s += qf[c * 8 + j] * kf[j];
        }
        mmax = fmaxf(mmax, s * scale);
    }
    // pass 2: sum of exp + weighted V accumulation
    float sum = 0.f;
    float yacc[64] = {};
    for (int n = 0; n < N_; n++) {
        float s = 0.f;
#pragma unroll
        for (int c = 0; c < 8; c++) {
            uint4 u = *((uint4*)&Ksh[n * HD_ + c * 8]);
            float kf[8]; unpack8(u, kf);
#pragma unroll
            for (int j = 0; j < 8; j++) s += qf[c * 8 + j] * kf[j];
        }
        float e = __expf(s * scale - mmax);
        sum += e;
#pragma unroll
        for (int c = 0; c < 8; c++) {
            uint4 u = *((uint4*)&Vsh[n * HD_ + c * 8]);
            float vf[8]; unpack8(u, vf);
#pragma unroll
            for (int j = 0; j < 8; j++) yacc[c * 8 + j] += e * vf[j];
        }
    }
    float inv = 1.f / sum;
    bf16* yp = y + ((size_t)(b * T_ + t) * D_) + h * HD_;
#pragma unroll
    for (int d = 0; d < 64; d++) yp[d] = __float2bfloat16(yacc[d] * inv);
}

// ------- stylization: LN(y)*(1+scale)+shift, then silu; y bf16, rest f32 --
__global__ __launch_bounds__(256) void styl_kernel(const bf16* __restrict__ y,
                                                   const float* __restrict__ g,
                                                   const float* __restrict__ bb,
                                                   const float* __restrict__ embo,
                                                   bf16* __restrict__ a) {
    int row = blockIdx.x;        // b*T + t
    int b = row >> 10;
    const bf16* rp = y + (size_t)row * D_;
    float s = 0.f, s2 = 0.f;
    for (int i = threadIdx.x; i < D_; i += 256) {
        float v = __bfloat162float(rp[i]); s += v; s2 += v * v;
    }
    for (int off = 32; off; off >>= 1) {
        s  += __shfl_down(s,  off, 64);
        s2 += __shfl_down(s2, off, 64);
    }
    __shared__ float ps[4], ps2[4];
    __shared__ float smu, srstd;
    int wid = threadIdx.x >> 6, lid = threadIdx.x & 63;
    if (lid == 0) { ps[wid] = s; ps2[wid] = s2; }
    __syncthreads();
    if (threadIdx.x == 0) {
        float t = ps[0] + ps[1] + ps[2] + ps[3];
        float t2 = ps2[0] + ps2[1] + ps2[2] + ps2[3];
        float m = t / D_;
        float var = t2 / D_ - m * m;
        smu = m; srstd = rsqrtf(var + 1e-5f);
    }
    __syncthreads();
    float mu = smu, rstd = srstd;
    for (int i = threadIdx.x; i < D_; i += 256) {
        float v = __bfloat162float(rp[i]);
        float nrm = (v - mu) * rstd * g[i] + bb[i];
        float sc = embo[b * 2048 + i];
        float sh = embo[b * 2048 + 1024 + i];
        float hh = nrm * (1.f + sc) + sh;
        float sig = 1.f / (1.f + __expf(-hh));
        a[(size_t)row * D_ + i] = __float2bfloat16(hh * sig);
    }
}

extern "C" void kernel_launch(void* const* d_in, const int* in_sizes, int n_in,
                              void* d_out, int out_size, void* d_ws, size_t ws_size,
                              hipStream_t stream) {
    const float* x    = (const float*)d_in[0];
    const float* xf   = (const float*)d_in[1];
    const float* emb  = (const float*)d_in[2];
    const float* ln_g = (const float*)d_in[3];
    const float* ln_b = (const float*)d_in[4];
    const float* cln_g= (const float*)d_in[5];
    const float* cln_b= (const float*)d_in[6];
    const float* Wq   = (const float*)d_in[7];
    const float* bq   = (const float*)d_in[8];
    const float* Wk   = (const float*)d_in[9];
    const float* bk   = (const float*)d_in[10];
    const float* Wv   = (const float*)d_in[11];
    const float* bv   = (const float*)d_in[12];
    const float* sln_g= (const float*)d_in[13];
    const float* sln_b= (const float*)d_in[14];
    const float* Wemb = (const float*)d_in[15];
    const float* bemb = (const float*)d_in[16];
    const float* Wout = (const float*)d_in[17];
    const float* bout = (const float*)d_in[18];
    float* out = (float*)d_out;

    char* w = (char*)d_ws;
    bf16*  xn   = (bf16*)(w);                        // 8192x1024  bf16  16 MB
    bf16*  xfn  = (bf16*)(w + 16777216);             // 2048x768   bf16   3 MB
    bf16*  q    = (bf16*)(w + 19922944);             // 8192x1024  bf16  16 MB
    bf16*  k    = (bf16*)(w + 36700160);             // 2048x1024  bf16   4 MB
    bf16*  v    = (bf16*)(w + 40894464);             // 2048x1024  bf16   4 MB
    bf16*  y    = (bf16*)(w + 45088768);             // 8192x1024  bf16  16 MB
    bf16*  a    = (bf16*)(w + 61865984);             // 8192x1024  bf16  16 MB
    float* embo = (float*)(w + 78643200);            // 8x2048     f32   64 KB

    ln_kernel<<<B_ * T_, 256, 0, stream>>>(x, ln_g, ln_b, xn, D_);
    ln_kernel<<<B_ * N_, 256, 0, stream>>>(xf, cln_g, cln_b, xfn, L_);

    gemm_kernel<false><<<dim3(16, 128), 256, 0, stream>>>(xn, Wq, bq, (const float*)nullptr, q, B_*T_, D_, D_);
    gemm_kernel<false><<<dim3(16, 32), 256, 0, stream>>>(xfn, Wk, bk, (const float*)nullptr, k, B_*N_, D_, L_);
    gemm_kernel<false><<<dim3(16, 32), 256, 0, stream>>>(xfn, Wv, bv, (const float*)nullptr, v, B_*N_, D_, L_);

    emb_kernel<<<64, 256, 0, stream>>>(emb, Wemb, bemb, embo);

    attn_kernel<<<dim3(B_ * H_, T_ / 256), 256, 0, stream>>>(q, k, v, y);

    styl_kernel<<<B_ * T_, 256, 0, stream>>>(y, sln_g, sln_b, embo, a);

    gemm_kernel<true><<<dim3(16, 128), 256, 0, stream>>>(a, Wout, bout, x, out, B_*T_, D_, D_);
}

// Round 3
// 400.659 us; speedup vs baseline: 3.2182x; 3.2182x over previous
//
#include <hip/hip_runtime.h>
#include <hip/hip_bf16.h>

typedef __hip_bfloat16 bf16;
typedef unsigned short ushort;
typedef __attribute__((ext_vector_type(8))) short bf16x8;
typedef __attribute__((ext_vector_type(4))) float f32x4;

#define B_ 8
#define T_ 1024
#define D_ 1024
#define N_ 256
#define L_ 768
#define H_ 16
#define HD_ 64
#define TE_ 2048

// ---------------- LayerNorm: one block (256 thr) per row; f32 in, bf16 out
__global__ __launch_bounds__(256) void ln_kernel(const float* __restrict__ in,
                                                 const float* __restrict__ g,
                                                 const float* __restrict__ bb,
                                                 bf16* __restrict__ out, int cols) {
    int row = blockIdx.x;
    const float* rp = in + (size_t)row * cols;
    float s = 0.f, s2 = 0.f;
    for (int i = threadIdx.x; i < cols; i += 256) {
        float v = rp[i]; s += v; s2 += v * v;
    }
    for (int off = 32; off; off >>= 1) {
        s  += __shfl_down(s,  off, 64);
        s2 += __shfl_down(s2, off, 64);
    }
    __shared__ float ps[4], ps2[4];
    __shared__ float smu, srstd;
    int wid = threadIdx.x >> 6, lid = threadIdx.x & 63;
    if (lid == 0) { ps[wid] = s; ps2[wid] = s2; }
    __syncthreads();
    if (threadIdx.x == 0) {
        float t = ps[0] + ps[1] + ps[2] + ps[3];
        float t2 = ps2[0] + ps2[1] + ps2[2] + ps2[3];
        float m = t / cols;
        float var = t2 / cols - m * m;
        smu = m; srstd = rsqrtf(var + 1e-5f);
    }
    __syncthreads();
    float mu = smu, rstd = srstd;
    for (int i = threadIdx.x; i < cols; i += 256) {
        float v = rp[i];
        float o = (v - mu) * rstd * g[i] + bb[i];
        out[(size_t)row * cols + i] = __float2bfloat16(o);
    }
}

// -------- transpose + f32->bf16 convert: W (K x N) -> Wt (N x K) ----------
__global__ __launch_bounds__(256) void tcvt_kernel(const float* __restrict__ W,
                                                   bf16* __restrict__ Wt,
                                                   int K, int Nc) {
    __shared__ ushort t[64][65];
    int k0 = blockIdx.y * 64, n0 = blockIdx.x * 64;
    int tid = threadIdx.x;
#pragma unroll
    for (int i = 0; i < 16; i++) {
        int e = tid + i * 256;
        int r = e >> 6, c = e & 63;
        bf16 hv = __float2bfloat16(W[(size_t)(k0 + r) * Nc + n0 + c]);
        t[r][c] = *(ushort*)&hv;
    }
    __syncthreads();
#pragma unroll
    for (int i = 0; i < 16; i++) {
        int e = tid + i * 256;
        int r = e >> 6, c = e & 63;
        ushort uv = t[c][r];
        Wt[(size_t)(n0 + r) * K + k0 + c] = *(bf16*)&uv;
    }
}

// -------- MFMA GEMM: C(MxN) = A(MxK,bf16) @ Wt(NxK,bf16)^T + bias [+res] --
// 128x128 tile, BK=32, 4 waves each 64x64 (4x4 of 16x16x32 mfma)
template <int OUT_F32>
__global__ __launch_bounds__(256) void gemm_mfma(const bf16* __restrict__ A,
                                                 const bf16* __restrict__ Bt,
                                                 const float* __restrict__ bias,
                                                 const float* __restrict__ res,
                                                 void* __restrict__ Cout,
                                                 int M, int Ncols, int K) {
    __shared__ ushort Ash[128 * 40];
    __shared__ ushort Bsh[128 * 40];
    int tid = threadIdx.x;
    int w = tid >> 6, lane = tid & 63;
    int quad = lane >> 4, l15 = lane & 15;
    int m0 = blockIdx.y * 128, n0 = blockIdx.x * 128;
    int wm = (w >> 1) * 64, wn = (w & 1) * 64;
    f32x4 acc[4][4] = {};
    const ushort* Ap = (const ushort*)A;
    const ushort* Bp = (const ushort*)Bt;
    for (int kt = 0; kt < K; kt += 32) {
#pragma unroll
        for (int i = 0; i < 2; i++) {
            int e = tid + i * 256;
            int r = e >> 2, c = e & 3;
            uint4 da = *(const uint4*)&Ap[(size_t)(m0 + r) * K + kt + c * 8];
            *(uint4*)&Ash[r * 40 + c * 8] = da;
            uint4 db = *(const uint4*)&Bp[(size_t)(n0 + r) * K + kt + c * 8];
            *(uint4*)&Bsh[r * 40 + c * 8] = db;
        }
        __syncthreads();
        bf16x8 af[4], bfr[4];
#pragma unroll
        for (int mt = 0; mt < 4; mt++)
            af[mt] = *(bf16x8*)&Ash[(wm + mt * 16 + l15) * 40 + quad * 8];
#pragma unroll
        for (int nt = 0; nt < 4; nt++)
            bfr[nt] = *(bf16x8*)&Bsh[(wn + nt * 16 + l15) * 40 + quad * 8];
#pragma unroll
        for (int mt = 0; mt < 4; mt++)
#pragma unroll
            for (int nt = 0; nt < 4; nt++)
                acc[mt][nt] = __builtin_amdgcn_mfma_f32_16x16x32_bf16(af[mt], bfr[nt], acc[mt][nt], 0, 0, 0);
        __syncthreads();
    }
    // epilogue: D row = quad*4+reg, col = l15
#pragma unroll
    for (int mt = 0; mt < 4; mt++) {
#pragma unroll
        for (int nt = 0; nt < 4; nt++) {
#pragma unroll
            for (int reg = 0; reg < 4; reg++) {
                int row = m0 + wm + mt * 16 + quad * 4 + reg;
                int col = n0 + wn + nt * 16 + l15;
                float v = acc[mt][nt][reg] + bias[col];
                if (OUT_F32) {
                    v += res[(size_t)row * Ncols + col];
                    ((float*)Cout)[(size_t)row * Ncols + col] = v;
                } else {
                    ((bf16*)Cout)[(size_t)row * Ncols + col] = __float2bfloat16(v);
                }
            }
        }
    }
}

// ---------------- silu(emb) @ Wemb + bemb  (M=8, tiny); all f32 ----------
__global__ __launch_bounds__(256) void emb_kernel(const float* __restrict__ emb,
                                                  const float* __restrict__ Wemb,
                                                  const float* __restrict__ bemb,
                                                  float* __restrict__ embo) {
    int idx = blockIdx.x * 256 + threadIdx.x;
    int b = idx >> 11;
    int j = idx & 2047;
    __shared__ float se[TE_];
    for (int e = threadIdx.x; e < TE_; e += 256) {
        float x = emb[b * TE_ + e];
        se[e] = x / (1.f + __expf(-x));
    }
    __syncthreads();
    float acc = 0.f;
    for (int e = 0; e < TE_; e++)
        acc += se[e] * Wemb[(size_t)e * 2048 + j];
    embo[idx] = acc + bemb[j];
}

// ---------------- MFMA attention: block = 64 q-rows x one (b,h) ----------
// LDS: KV region (K then Vt), P region (Q then P). XOR-chunk swizzle.
__global__ __launch_bounds__(256) void attn_mfma(const bf16* __restrict__ q,
                                                 const bf16* __restrict__ k,
                                                 const bf16* __restrict__ v,
                                                 bf16* __restrict__ y) {
    __shared__ ushort KV[N_ * HD_];   // 32768 B
    __shared__ ushort P[64 * N_];     // 32768 B (Q overlays first 8 KB in phase 1)
    int tid = threadIdx.x;
    int w = tid >> 6, lane = tid & 63;
    int quad = lane >> 4, l15 = lane & 15;
    int t0 = blockIdx.x * 64;
    int bh = blockIdx.y;
    int b = bh >> 4, h = bh & 15;

    const ushort* kp = (const ushort*)k;
    const ushort* qp = (const ushort*)q;
    const ushort* vp = (const ushort*)v;

    // stage K: rows n (64 bf16 each), chunk swizzle c^(n&7)
#pragma unroll
    for (int i = 0; i < 8; i++) {
        int e = tid + i * 256;
        int n = e >> 3, c = e & 7;
        uint4 d = *(const uint4*)&kp[((size_t)(b * N_ + n) * D_) + h * 64 + c * 8];
        *(uint4*)&KV[n * 64 + ((c ^ (n & 7)) * 8)] = d;
    }
    // stage Q into P region: rows m (64 bf16), chunk swizzle c^(m&7)
#pragma unroll
    for (int i = 0; i < 2; i++) {
        int e = tid + i * 256;
        int m = e >> 3, c = e & 7;
        uint4 d = *(const uint4*)&qp[((size_t)(b * T_ + t0 + m) * D_) + h * 64 + c * 8];
        *(uint4*)&P[m * 64 + ((c ^ (m & 7)) * 8)] = d;
    }
    __syncthreads();

    // S = Q K^T  (per wave: 16 q-rows x 256 ctx)
    int qrow = w * 16 + l15;
    bf16x8 aq[2];
#pragma unroll
    for (int kk = 0; kk < 2; kk++)
        aq[kk] = *(bf16x8*)&P[qrow * 64 + (((kk * 4 + quad) ^ (qrow & 7)) * 8)];
    f32x4 sf[16];
#pragma unroll
    for (int nt = 0; nt < 16; nt++) {
        int n = nt * 16 + l15;
        bf16x8 b0 = *(bf16x8*)&KV[n * 64 + (((0 + quad) ^ (n & 7)) * 8)];
        bf16x8 b1 = *(bf16x8*)&KV[n * 64 + (((4 + quad) ^ (n & 7)) * 8)];
        f32x4 z = {};
        f32x4 t = __builtin_amdgcn_mfma_f32_16x16x32_bf16(aq[0], b0, z, 0, 0, 0);
        sf[nt] = __builtin_amdgcn_mfma_f32_16x16x32_bf16(aq[1], b1, t, 0, 0, 0);
    }
    __syncthreads();   // all S mfma done -> Q and K regions reusable

    // one-shot softmax over N (rows = quad*4+reg)
    const float scale = 0.125f;
    float mx[4] = {-1e30f, -1e30f, -1e30f, -1e30f};
#pragma unroll
    for (int nt = 0; nt < 16; nt++)
#pragma unroll
        for (int reg = 0; reg < 4; reg++) mx[reg] = fmaxf(mx[reg], sf[nt][reg]);
#pragma unroll
    for (int off = 1; off < 16; off <<= 1)
#pragma unroll
        for (int reg = 0; reg < 4; reg++)
            mx[reg] = fmaxf(mx[reg], __shfl_xor(mx[reg], off, 64));
    float sm[4] = {0.f, 0.f, 0.f, 0.f};
#pragma unroll
    for (int nt = 0; nt < 16; nt++)
#pragma unroll
        for (int reg = 0; reg < 4; reg++) {
            float e = __expf((sf[nt][reg] - mx[reg]) * scale);
            sf[nt][reg] = e;
            sm[reg] += e;
        }
#pragma unroll
    for (int off = 1; off < 16; off <<= 1)
#pragma unroll
        for (int reg = 0; reg < 4; reg++)
            sm[reg] += __shfl_xor(sm[reg], off, 64);
    float inv[4];
#pragma unroll
    for (int reg = 0; reg < 4; reg++) inv[reg] = 1.f / sm[reg];

    // write P (bf16, A-operand layout w/ swizzle) — overwrites Q (dead)
#pragma unroll
    for (int nt = 0; nt < 16; nt++)
#pragma unroll
        for (int reg = 0; reg < 4; reg++) {
            int r = w * 16 + quad * 4 + reg;
            int colc = nt * 2 + (l15 >> 3);
            int addr = r * 256 + ((colc ^ (r & 7)) * 8) + (l15 & 7);
            bf16 hv = __float2bfloat16(sf[nt][reg]);
            P[addr] = *(ushort*)&hv;
        }
    // stage V transposed into KV region (K dead): Vt[d][n]
#pragma unroll
    for (int i = 0; i < 8; i++) {
        int e = tid + i * 256;
        int n = e & 255, dc = e >> 8;
        uint4 dv = *(const uint4*)&vp[((size_t)(b * N_ + n) * D_) + h * 64 + dc * 8];
        ushort vals[8];
        *(uint4*)vals = dv;
#pragma unroll
        for (int j = 0; j < 8; j++) {
            int d = dc * 8 + j;
            KV[d * 256 + (((n >> 3) ^ (d & 7)) * 8) + (n & 7)] = vals[j];
        }
    }
    __syncthreads();

    // O = P @ V : per wave 16 rows x 64 d, K-dim = 256
    f32x4 of[4] = {};
    int prow = w * 16 + l15;
#pragma unroll
    for (int kk = 0; kk < 8; kk++) {
        bf16x8 ap = *(bf16x8*)&P[prow * 256 + (((kk * 4 + quad) ^ (prow & 7)) * 8)];
#pragma unroll
        for (int dt = 0; dt < 4; dt++) {
            int d = dt * 16 + l15;
            bf16x8 bv = *(bf16x8*)&KV[d * 256 + (((kk * 4 + quad) ^ (d & 7)) * 8)];
            of[dt] = __builtin_amdgcn_mfma_f32_16x16x32_bf16(ap, bv, of[dt], 0, 0, 0);
        }
    }
#pragma unroll
    for (int dt = 0; dt < 4; dt++)
#pragma unroll
        for (int reg = 0; reg < 4; reg++) {
            int r = t0 + w * 16 + quad * 4 + reg;
            y[((size_t)(b * T_ + r) * D_) + h * 64 + dt * 16 + l15] =
                __float2bfloat16(of[dt][reg] * inv[reg]);
        }
}

// ------- stylization: LN(y)*(1+scale)+shift, then silu; y bf16 -----------
__global__ __launch_bounds__(256) void styl_kernel(const bf16* __restrict__ y,
                                                   const float* __restrict__ g,
                                                   const float* __restrict__ bb,
                                                   const float* __restrict__ embo,
                                                   bf16* __restrict__ a) {
    int row = blockIdx.x;
    int b = row >> 10;
    const bf16* rp = y + (size_t)row * D_;
    float s = 0.f, s2 = 0.f;
    for (int i = threadIdx.x; i < D_; i += 256) {
        float v = __bfloat162float(rp[i]); s += v; s2 += v * v;
    }
    for (int off = 32; off; off >>= 1) {
        s  += __shfl_down(s,  off, 64);
        s2 += __shfl_down(s2, off, 64);
    }
    __shared__ float ps[4], ps2[4];
    __shared__ float smu, srstd;
    int wid = threadIdx.x >> 6, lid = threadIdx.x & 63;
    if (lid == 0) { ps[wid] = s; ps2[wid] = s2; }
    __syncthreads();
    if (threadIdx.x == 0) {
        float t = ps[0] + ps[1] + ps[2] + ps[3];
        float t2 = ps2[0] + ps2[1] + ps2[2] + ps2[3];
        float m = t / D_;
        float var = t2 / D_ - m * m;
        smu = m; srstd = rsqrtf(var + 1e-5f);
    }
    __syncthreads();
    float mu = smu, rstd = srstd;
    for (int i = threadIdx.x; i < D_; i += 256) {
        float v = __bfloat162float(rp[i]);
        float nrm = (v - mu) * rstd * g[i] + bb[i];
        float sc = embo[b * 2048 + i];
        float sh = embo[b * 2048 + 1024 + i];
        float hh = nrm * (1.f + sc) + sh;
        float sig = 1.f / (1.f + __expf(-hh));
        a[(size_t)row * D_ + i] = __float2bfloat16(hh * sig);
    }
}

extern "C" void kernel_launch(void* const* d_in, const int* in_sizes, int n_in,
                              void* d_out, int out_size, void* d_ws, size_t ws_size,
                              hipStream_t stream) {
    const float* x    = (const float*)d_in[0];
    const float* xf   = (const float*)d_in[1];
    const float* emb  = (const float*)d_in[2];
    const float* ln_g = (const float*)d_in[3];
    const float* ln_b = (const float*)d_in[4];
    const float* cln_g= (const float*)d_in[5];
    const float* cln_b= (const float*)d_in[6];
    const float* Wq   = (const float*)d_in[7];
    const float* bq   = (const float*)d_in[8];
    const float* Wk   = (const float*)d_in[9];
    const float* bk   = (const float*)d_in[10];
    const float* Wv   = (const float*)d_in[11];
    const float* bv   = (const float*)d_in[12];
    const float* sln_g= (const float*)d_in[13];
    const float* sln_b= (const float*)d_in[14];
    const float* Wemb = (const float*)d_in[15];
    const float* bemb = (const float*)d_in[16];
    const float* Wout = (const float*)d_in[17];
    const float* bout = (const float*)d_in[18];
    float* out = (float*)d_out;

    char* wsp = (char*)d_ws;
    bf16*  xn   = (bf16*)(wsp);                   // 8192x1024 bf16 16MB (reused as y)
    bf16*  xfn  = (bf16*)(wsp + 16777216);        // 2048x768  bf16  3MB
    bf16*  q    = (bf16*)(wsp + 19922944);        // 8192x1024 bf16 16MB (reused as a)
    bf16*  kbuf = (bf16*)(wsp + 36700160);        // 2048x1024 bf16  4MB
    bf16*  vbuf = (bf16*)(wsp + 40894464);        // 2048x1024 bf16  4MB
    float* embo = (float*)(wsp + 45088768);       // 8x2048    f32  64KB
    bf16*  wqt  = (bf16*)(wsp + 45154304);        // 1024x1024 bf16  2MB
    bf16*  wkt  = (bf16*)(wsp + 47251456);        // 1024x768  bf16 1.5MB
    bf16*  wvt  = (bf16*)(wsp + 48824320);        // 1024x768  bf16 1.5MB
    bf16*  wot  = (bf16*)(wsp + 50397184);        // 1024x1024 bf16  2MB
    bf16*  ybuf = xn;   // alias: xn dead after Q-proj
    bf16*  abuf = q;    // alias: q dead after attn

    ln_kernel<<<B_ * T_, 256, 0, stream>>>(x, ln_g, ln_b, xn, D_);
    ln_kernel<<<B_ * N_, 256, 0, stream>>>(xf, cln_g, cln_b, xfn, L_);

    tcvt_kernel<<<dim3(16, 16), 256, 0, stream>>>(Wq,   wqt, D_, D_);
    tcvt_kernel<<<dim3(16, 12), 256, 0, stream>>>(Wk,   wkt, L_, D_);
    tcvt_kernel<<<dim3(16, 12), 256, 0, stream>>>(Wv,   wvt, L_, D_);
    tcvt_kernel<<<dim3(16, 16), 256, 0, stream>>>(Wout, wot, D_, D_);

    gemm_mfma<0><<<dim3(8, 64), 256, 0, stream>>>(xn,  wqt, bq, nullptr, q,    B_*T_, D_, D_);
    gemm_mfma<0><<<dim3(8, 16), 256, 0, stream>>>(xfn, wkt, bk, nullptr, kbuf, B_*N_, D_, L_);
    gemm_mfma<0><<<dim3(8, 16), 256, 0, stream>>>(xfn, wvt, bv, nullptr, vbuf, B_*N_, D_, L_);

    emb_kernel<<<64, 256, 0, stream>>>(emb, Wemb, bemb, embo);

    attn_mfma<<<dim3(16, 128), 256, 0, stream>>>(q, kbuf, vbuf, ybuf);

    styl_kernel<<<B_ * T_, 256, 0, stream>>>(ybuf, sln_g, sln_b, embo, abuf);

    gemm_mfma<1><<<dim3(8, 64), 256, 0, stream>>>(abuf, wot, bout, x, out, B_*T_, D_, D_);
}

// Round 4
// 313.307 us; speedup vs baseline: 4.1154x; 1.2788x over previous
//
#include <hip/hip_runtime.h>
#include <hip/hip_bf16.h>

typedef __hip_bfloat16 bf16;
typedef unsigned short ushort;
typedef __attribute__((ext_vector_type(8))) short bf16x8;
typedef __attribute__((ext_vector_type(4))) float f32x4;

#define B_ 8
#define T_ 1024
#define D_ 1024
#define N_ 256
#define L_ 768
#define H_ 16
#define HD_ 64
#define TE_ 2048

__device__ __forceinline__ void gld16(const void* g, void* l) {
    __builtin_amdgcn_global_load_lds((const __attribute__((address_space(1))) void*)g,
                                     (__attribute__((address_space(3))) void*)l,
                                     16, 0, 0);
}

// ------- fused LayerNorm for x (rows<8192, cols=1024) and xf (cols=768) ----
__global__ __launch_bounds__(256) void ln_both_kernel(const float* __restrict__ x,
                                                      const float* __restrict__ xf,
                                                      const float* __restrict__ g1,
                                                      const float* __restrict__ b1,
                                                      const float* __restrict__ g2,
                                                      const float* __restrict__ b2,
                                                      bf16* __restrict__ out1,
                                                      bf16* __restrict__ out2) {
    int row = blockIdx.x;
    const float *rp, *g, *bb; bf16* op; int cols;
    if (row < B_ * T_) {
        rp = x + (size_t)row * D_; g = g1; bb = b1; op = out1 + (size_t)row * D_; cols = D_;
    } else {
        int r = row - B_ * T_;
        rp = xf + (size_t)r * L_; g = g2; bb = b2; op = out2 + (size_t)r * L_; cols = L_;
    }
    float s = 0.f, s2 = 0.f;
    for (int i = threadIdx.x; i < cols; i += 256) {
        float v = rp[i]; s += v; s2 += v * v;
    }
    for (int off = 32; off; off >>= 1) {
        s  += __shfl_down(s,  off, 64);
        s2 += __shfl_down(s2, off, 64);
    }
    __shared__ float ps[4], ps2[4];
    __shared__ float smu, srstd;
    int wid = threadIdx.x >> 6, lid = threadIdx.x & 63;
    if (lid == 0) { ps[wid] = s; ps2[wid] = s2; }
    __syncthreads();
    if (threadIdx.x == 0) {
        float t = ps[0] + ps[1] + ps[2] + ps[3];
        float t2 = ps2[0] + ps2[1] + ps2[2] + ps2[3];
        float m = t / cols;
        float var = t2 / cols - m * m;
        smu = m; srstd = rsqrtf(var + 1e-5f);
    }
    __syncthreads();
    float mu = smu, rstd = srstd;
    for (int i = threadIdx.x; i < cols; i += 256) {
        float v = rp[i];
        op[i] = __float2bfloat16((v - mu) * rstd * g[i] + bb[i]);
    }
}

// -------- fused transpose+convert of all 4 weights: W(KxNc) -> Wt(NcxK) ----
__global__ __launch_bounds__(256) void tcvt4_kernel(const float* __restrict__ Wq,
                                                    const float* __restrict__ Wk,
                                                    const float* __restrict__ Wv,
                                                    const float* __restrict__ Wo,
                                                    bf16* __restrict__ wqt,
                                                    bf16* __restrict__ wkt,
                                                    bf16* __restrict__ wvt,
                                                    bf16* __restrict__ wot) {
    __shared__ ushort t[64][65];
    int y = blockIdx.y;
    const float* W; bf16* Wt; int K, ky;
    if (y < 16)      { W = Wq; Wt = wqt; K = 1024; ky = y; }
    else if (y < 28) { W = Wk; Wt = wkt; K = 768;  ky = y - 16; }
    else if (y < 40) { W = Wv; Wt = wvt; K = 768;  ky = y - 28; }
    else             { W = Wo; Wt = wot; K = 1024; ky = y - 40; }
    int k0 = ky * 64, n0 = blockIdx.x * 64;
    int tid = threadIdx.x;
#pragma unroll
    for (int i = 0; i < 16; i++) {
        int e = tid + i * 256;
        int r = e >> 6, c = e & 63;
        bf16 hv = __float2bfloat16(W[(size_t)(k0 + r) * D_ + n0 + c]);
        t[r][c] = *(ushort*)&hv;
    }
    __syncthreads();
#pragma unroll
    for (int i = 0; i < 16; i++) {
        int e = tid + i * 256;
        int r = e >> 6, c = e & 63;
        ushort uv = t[c][r];
        Wt[(size_t)(n0 + r) * K + k0 + c] = *(bf16*)&uv;
    }
}

// -------- MFMA GEMM w/ global_load_lds staging ----------------------------
// C(MxN) = A(MxK,bf16) @ Bt(NxK,bf16)^T + bias [+res]
// 128x128 tile, BK=32, LDS 128x32 unpadded, XOR-chunk swizzle (2-way max).
template <int OUT_F32>
__global__ __launch_bounds__(256) void gemm_mfma(const bf16* __restrict__ A,
                                                 const bf16* __restrict__ Bt,
                                                 const float* __restrict__ bias,
                                                 const float* __restrict__ res,
                                                 void* __restrict__ Cout,
                                                 int M, int Ncols, int K) {
    __shared__ ushort Ash[128 * 32];
    __shared__ ushort Bsh[128 * 32];
    int tid = threadIdx.x;
    int w = tid >> 6, lane = tid & 63;
    int quad = lane >> 4, l15 = lane & 15;
    int m0 = blockIdx.y * 128, n0 = blockIdx.x * 128;
    int wm = (w >> 1) * 64, wn = (w & 1) * 64;
    f32x4 acc[4][4] = {};
    const ushort* Ap = (const ushort*)A;
    const ushort* Bp = (const ushort*)Bt;
    int lr = lane >> 2;                        // row within 16-row group
    int gc = (lane & 3) ^ ((lane >> 3) & 3);   // which global chunk this lane fetches
    int fchunk = quad ^ ((l15 >> 1) & 3);      // fragment chunk position for reads
    for (int kt = 0; kt < K; kt += 32) {
#pragma unroll
        for (int j = 0; j < 2; j++) {
            int rbase = w * 32 + j * 16;
            gld16(&Ap[(size_t)(m0 + rbase + lr) * K + kt + gc * 8], &Ash[rbase * 32]);
            gld16(&Bp[(size_t)(n0 + rbase + lr) * K + kt + gc * 8], &Bsh[rbase * 32]);
        }
        __syncthreads();
        bf16x8 af[4], bfr[4];
#pragma unroll
        for (int mt = 0; mt < 4; mt++)
            af[mt] = *(bf16x8*)&Ash[(wm + mt * 16 + l15) * 32 + fchunk * 8];
#pragma unroll
        for (int nt = 0; nt < 4; nt++)
            bfr[nt] = *(bf16x8*)&Bsh[(wn + nt * 16 + l15) * 32 + fchunk * 8];
#pragma unroll
        for (int mt = 0; mt < 4; mt++)
#pragma unroll
            for (int nt = 0; nt < 4; nt++)
                acc[mt][nt] = __builtin_amdgcn_mfma_f32_16x16x32_bf16(af[mt], bfr[nt], acc[mt][nt], 0, 0, 0);
        __syncthreads();
    }
#pragma unroll
    for (int mt = 0; mt < 4; mt++) {
#pragma unroll
        for (int nt = 0; nt < 4; nt++) {
#pragma unroll
            for (int reg = 0; reg < 4; reg++) {
                int row = m0 + wm + mt * 16 + quad * 4 + reg;
                int col = n0 + wn + nt * 16 + l15;
                float v = acc[mt][nt][reg] + bias[col];
                if (OUT_F32) {
                    v += res[(size_t)row * Ncols + col];
                    ((float*)Cout)[(size_t)row * Ncols + col] = v;
                } else {
                    ((bf16*)Cout)[(size_t)row * Ncols + col] = __float2bfloat16(v);
                }
            }
        }
    }
}

// -------- emb stage 1: partial dot over 256-k slab; grid (32 jc, 8 ks) -----
__global__ __launch_bounds__(256) void emb1_kernel(const float* __restrict__ emb,
                                                   const float* __restrict__ Wemb,
                                                   float* __restrict__ part) {
    __shared__ float se[8 * 256];
    __shared__ float red[16 * 8 * 64];
    int tid = threadIdx.x;
    int j0 = blockIdx.x * 64;
    int ks = blockIdx.y;
    int tx = tid & 15, ty = tid >> 4;
#pragma unroll
    for (int b = 0; b < 8; b++) {
        float xv = emb[b * TE_ + ks * 256 + tid];
        se[b * 256 + tid] = xv / (1.f + __expf(-xv));
    }
    __syncthreads();
    float acc[8][4] = {};
#pragma unroll 4
    for (int i = 0; i < 16; i++) {
        int e = ty + 16 * i;
        float4 wv = *(const float4*)&Wemb[(size_t)(ks * 256 + e) * 2048 + j0 + tx * 4];
#pragma unroll
        for (int b = 0; b < 8; b++) {
            float s = se[b * 256 + e];
            acc[b][0] += s * wv.x; acc[b][1] += s * wv.y;
            acc[b][2] += s * wv.z; acc[b][3] += s * wv.w;
        }
    }
#pragma unroll
    for (int b = 0; b < 8; b++)
#pragma unroll
        for (int m = 0; m < 4; m++)
            red[(ty * 8 + b) * 64 + tx * 4 + m] = acc[b][m];
    __syncthreads();
    for (int o = tid; o < 512; o += 256) {
        int b = o >> 6, jl = o & 63;
        float s = 0.f;
#pragma unroll
        for (int t2 = 0; t2 < 16; t2++) s += red[(t2 * 8 + b) * 64 + jl];
        part[((size_t)ks * 8 + b) * 2048 + j0 + jl] = s;
    }
}

// -------- emb stage 2: reduce 8 partials + bias ---------------------------
__global__ __launch_bounds__(256) void emb2_kernel(const float* __restrict__ part,
                                                   const float* __restrict__ bemb,
                                                   float* __restrict__ embo) {
    int o = blockIdx.x * 256 + threadIdx.x;   // 16384 outputs
    int b = o >> 11, j = o & 2047;
    float s = bemb[j];
#pragma unroll
    for (int ks = 0; ks < 8; ks++) s += part[((size_t)ks * 8 + b) * 2048 + j];
    embo[o] = s;
}

// ---------------- MFMA attention: block = 64 q-rows x one (b,h) ----------
__global__ __launch_bounds__(256) void attn_mfma(const bf16* __restrict__ q,
                                                 const bf16* __restrict__ k,
                                                 const bf16* __restrict__ v,
                                                 bf16* __restrict__ y) {
    __shared__ ushort KV[N_ * HD_];   // 32768 B
    __shared__ ushort P[64 * N_];     // 32768 B
    int tid = threadIdx.x;
    int w = tid >> 6, lane = tid & 63;
    int quad = lane >> 4, l15 = lane & 15;
    int t0 = blockIdx.x * 64;
    int bh = blockIdx.y;
    int b = bh >> 4, h = bh & 15;

    const ushort* kp = (const ushort*)k;
    const ushort* qp = (const ushort*)q;
    const ushort* vp = (const ushort*)v;

#pragma unroll
    for (int i = 0; i < 8; i++) {
        int e = tid + i * 256;
        int n = e >> 3, c = e & 7;
        uint4 d = *(const uint4*)&kp[((size_t)(b * N_ + n) * D_) + h * 64 + c * 8];
        *(uint4*)&KV[n * 64 + ((c ^ (n & 7)) * 8)] = d;
    }
#pragma unroll
    for (int i = 0; i < 2; i++) {
        int e = tid + i * 256;
        int m = e >> 3, c = e & 7;
        uint4 d = *(const uint4*)&qp[((size_t)(b * T_ + t0 + m) * D_) + h * 64 + c * 8];
        *(uint4*)&P[m * 64 + ((c ^ (m & 7)) * 8)] = d;
    }
    __syncthreads();

    int qrow = w * 16 + l15;
    bf16x8 aq[2];
#pragma unroll
    for (int kk = 0; kk < 2; kk++)
        aq[kk] = *(bf16x8*)&P[qrow * 64 + (((kk * 4 + quad) ^ (qrow & 7)) * 8)];
    f32x4 sf[16];
#pragma unroll
    for (int nt = 0; nt < 16; nt++) {
        int n = nt * 16 + l15;
        bf16x8 b0 = *(bf16x8*)&KV[n * 64 + (((0 + quad) ^ (n & 7)) * 8)];
        bf16x8 b1 = *(bf16x8*)&KV[n * 64 + (((4 + quad) ^ (n & 7)) * 8)];
        f32x4 z = {};
        f32x4 t = __builtin_amdgcn_mfma_f32_16x16x32_bf16(aq[0], b0, z, 0, 0, 0);
        sf[nt] = __builtin_amdgcn_mfma_f32_16x16x32_bf16(aq[1], b1, t, 0, 0, 0);
    }
    __syncthreads();

    const float scale = 0.125f;
    float mx[4] = {-1e30f, -1e30f, -1e30f, -1e30f};
#pragma unroll
    for (int nt = 0; nt < 16; nt++)
#pragma unroll
        for (int reg = 0; reg < 4; reg++) mx[reg] = fmaxf(mx[reg], sf[nt][reg]);
#pragma unroll
    for (int off = 1; off < 16; off <<= 1)
#pragma unroll
        for (int reg = 0; reg < 4; reg++)
            mx[reg] = fmaxf(mx[reg], __shfl_xor(mx[reg], off, 64));
    float sm[4] = {0.f, 0.f, 0.f, 0.f};
#pragma unroll
    for (int nt = 0; nt < 16; nt++)
#pragma unroll
        for (int reg = 0; reg < 4; reg++) {
            float e = __expf((sf[nt][reg] - mx[reg]) * scale);
            sf[nt][reg] = e;
            sm[reg] += e;
        }
#pragma unroll
    for (int off = 1; off < 16; off <<= 1)
#pragma unroll
        for (int reg = 0; reg < 4; reg++)
            sm[reg] += __shfl_xor(sm[reg], off, 64);
    float inv[4];
#pragma unroll
    for (int reg = 0; reg < 4; reg++) inv[reg] = 1.f / sm[reg];

#pragma unroll
    for (int nt = 0; nt < 16; nt++)
#pragma unroll
        for (int reg = 0; reg < 4; reg++) {
            int r = w * 16 + quad * 4 + reg;
            int colc = nt * 2 + (l15 >> 3);
            int addr = r * 256 + ((colc ^ (r & 7)) * 8) + (l15 & 7);
            bf16 hv = __float2bfloat16(sf[nt][reg]);
            P[addr] = *(ushort*)&hv;
        }
#pragma unroll
    for (int i = 0; i < 8; i++) {
        int e = tid + i * 256;
        int n = e & 255, dc = e >> 8;
        uint4 dv = *(const uint4*)&vp[((size_t)(b * N_ + n) * D_) + h * 64 + dc * 8];
        ushort vals[8];
        *(uint4*)vals = dv;
#pragma unroll
        for (int j = 0; j < 8; j++) {
            int d = dc * 8 + j;
            KV[d * 256 + (((n >> 3) ^ (d & 7)) * 8) + (n & 7)] = vals[j];
        }
    }
    __syncthreads();

    f32x4 of[4] = {};
    int prow = w * 16 + l15;
#pragma unroll
    for (int kk = 0; kk < 8; kk++) {
        bf16x8 ap = *(bf16x8*)&P[prow * 256 + (((kk * 4 + quad) ^ (prow & 7)) * 8)];
#pragma unroll
        for (int dt = 0; dt < 4; dt++) {
            int d = dt * 16 + l15;
            bf16x8 bv = *(bf16x8*)&KV[d * 256 + (((kk * 4 + quad) ^ (d & 7)) * 8)];
            of[dt] = __builtin_amdgcn_mfma_f32_16x16x32_bf16(ap, bv, of[dt], 0, 0, 0);
        }
    }
#pragma unroll
    for (int dt = 0; dt < 4; dt++)
#pragma unroll
        for (int reg = 0; reg < 4; reg++) {
            int r = t0 + w * 16 + quad * 4 + reg;
            y[((size_t)(b * T_ + r) * D_) + h * 64 + dt * 16 + l15] =
                __float2bfloat16(of[dt][reg] * inv[reg]);
        }
}

// ------- stylization: LN(y)*(1+scale)+shift, then silu; y bf16 -----------
__global__ __launch_bounds__(256) void styl_kernel(const bf16* __restrict__ y,
                                                   const float* __restrict__ g,
                                                   const float* __restrict__ bb,
                                                   const float* __restrict__ embo,
                                                   bf16* __restrict__ a) {
    int row = blockIdx.x;
    int b = row >> 10;
    const bf16* rp = y + (size_t)row * D_;
    float s = 0.f, s2 = 0.f;
    for (int i = threadIdx.x; i < D_; i += 256) {
        float v = __bfloat162float(rp[i]); s += v; s2 += v * v;
    }
    for (int off = 32; off; off >>= 1) {
        s  += __shfl_down(s,  off, 64);
        s2 += __shfl_down(s2, off, 64);
    }
    __shared__ float ps[4], ps2[4];
    __shared__ float smu, srstd;
    int wid = threadIdx.x >> 6, lid = threadIdx.x & 63;
    if (lid == 0) { ps[wid] = s; ps2[wid] = s2; }
    __syncthreads();
    if (threadIdx.x == 0) {
        float t = ps[0] + ps[1] + ps[2] + ps[3];
        float t2 = ps2[0] + ps2[1] + ps2[2] + ps2[3];
        float m = t / D_;
        float var = t2 / D_ - m * m;
        smu = m; srstd = rsqrtf(var + 1e-5f);
    }
    __syncthreads();
    float mu = smu, rstd = srstd;
    for (int i = threadIdx.x; i < D_; i += 256) {
        float v = __bfloat162float(rp[i]);
        float nrm = (v - mu) * rstd * g[i] + bb[i];
        float sc = embo[b * 2048 + i];
        float sh = embo[b * 2048 + 1024 + i];
        float hh = nrm * (1.f + sc) + sh;
        float sig = 1.f / (1.f + __expf(-hh));
        a[(size_t)row * D_ + i] = __float2bfloat16(hh * sig);
    }
}

extern "C" void kernel_launch(void* const* d_in, const int* in_sizes, int n_in,
                              void* d_out, int out_size, void* d_ws, size_t ws_size,
                              hipStream_t stream) {
    const float* x    = (const float*)d_in[0];
    const float* xf   = (const float*)d_in[1];
    const float* emb  = (const float*)d_in[2];
    const float* ln_g = (const float*)d_in[3];
    const float* ln_b = (const float*)d_in[4];
    const float* cln_g= (const float*)d_in[5];
    const float* cln_b= (const float*)d_in[6];
    const float* Wq   = (const float*)d_in[7];
    const float* bq   = (const float*)d_in[8];
    const float* Wk   = (const float*)d_in[9];
    const float* bk   = (const float*)d_in[10];
    const float* Wv   = (const float*)d_in[11];
    const float* bv   = (const float*)d_in[12];
    const float* sln_g= (const float*)d_in[13];
    const float* sln_b= (const float*)d_in[14];
    const float* Wemb = (const float*)d_in[15];
    const float* bemb = (const float*)d_in[16];
    const float* Wout = (const float*)d_in[17];
    const float* bout = (const float*)d_in[18];
    float* out = (float*)d_out;

    char* wsp = (char*)d_ws;
    bf16*  xn   = (bf16*)(wsp);                   // 8192x1024 bf16 16MB (reused as y)
    bf16*  xfn  = (bf16*)(wsp + 16777216);        // 2048x768  bf16  3MB
    bf16*  q    = (bf16*)(wsp + 19922944);        // 8192x1024 bf16 16MB (reused as a)
    bf16*  kbuf = (bf16*)(wsp + 36700160);        // 2048x1024 bf16  4MB
    bf16*  vbuf = (bf16*)(wsp + 40894464);        // 2048x1024 bf16  4MB
    float* embo = (float*)(wsp + 45088768);       // 8x2048    f32  64KB
    bf16*  wqt  = (bf16*)(wsp + 45154304);        // 1024x1024 bf16  2MB
    bf16*  wkt  = (bf16*)(wsp + 47251456);        // 1024x768  bf16 1.5MB
    bf16*  wvt  = (bf16*)(wsp + 48824320);        // 1024x768  bf16 1.5MB
    bf16*  wot  = (bf16*)(wsp + 50397184);        // 1024x1024 bf16  2MB
    float* part = (float*)(wsp + 52494336);       // 8x8x2048  f32  512KB
    bf16*  ybuf = xn;   // alias: xn dead after Q-proj
    bf16*  abuf = q;    // alias: q dead after attn

    ln_both_kernel<<<B_ * T_ + B_ * N_, 256, 0, stream>>>(x, xf, ln_g, ln_b, cln_g, cln_b, xn, xfn);

    tcvt4_kernel<<<dim3(16, 56), 256, 0, stream>>>(Wq, Wk, Wv, Wout, wqt, wkt, wvt, wot);

    emb1_kernel<<<dim3(32, 8), 256, 0, stream>>>(emb, Wemb, part);
    emb2_kernel<<<64, 256, 0, stream>>>(part, bemb, embo);

    gemm_mfma<0><<<dim3(8, 64), 256, 0, stream>>>(xn,  wqt, bq, nullptr, q,    B_*T_, D_, D_);
    gemm_mfma<0><<<dim3(8, 16), 256, 0, stream>>>(xfn, wkt, bk, nullptr, kbuf, B_*N_, D_, L_);
    gemm_mfma<0><<<dim3(8, 16), 256, 0, stream>>>(xfn, wvt, bv, nullptr, vbuf, B_*N_, D_, L_);

    attn_mfma<<<dim3(16, 128), 256, 0, stream>>>(q, kbuf, vbuf, ybuf);

    styl_kernel<<<B_ * T_, 256, 0, stream>>>(ybuf, sln_g, sln_b, embo, abuf);

    gemm_mfma<1><<<dim3(8, 64), 256, 0, stream>>>(abuf, wot, bout, x, out, B_*T_, D_, D_);
}

// Round 5
// 277.384 us; speedup vs baseline: 4.6484x; 1.1295x over previous
//
#include <hip/hip_runtime.h>
#include <hip/hip_bf16.h>

typedef __hip_bfloat16 bf16;
typedef unsigned short ushort;
typedef __attribute__((ext_vector_type(8))) short bf16x8;
typedef __attribute__((ext_vector_type(4))) float f32x4;

#define B_ 8
#define T_ 1024
#define D_ 1024
#define N_ 256
#define L_ 768
#define H_ 16
#define HD_ 64
#define TE_ 2048

__device__ __forceinline__ void gld16(const void* g, void* l) {
    __builtin_amdgcn_global_load_lds((const __attribute__((address_space(1))) void*)g,
                                     (__attribute__((address_space(3))) void*)l,
                                     16, 0, 0);
}

// ------- fused LayerNorm for x (rows<8192, cols=1024) and xf (cols=768) ----
__global__ __launch_bounds__(256) void ln_both_kernel(const float* __restrict__ x,
                                                      const float* __restrict__ xf,
                                                      const float* __restrict__ g1,
                                                      const float* __restrict__ b1,
                                                      const float* __restrict__ g2,
                                                      const float* __restrict__ b2,
                                                      bf16* __restrict__ out1,
                                                      bf16* __restrict__ out2) {
    int row = blockIdx.x;
    const float *rp, *g, *bb; bf16* op; int cols;
    if (row < B_ * T_) {
        rp = x + (size_t)row * D_; g = g1; bb = b1; op = out1 + (size_t)row * D_; cols = D_;
    } else {
        int r = row - B_ * T_;
        rp = xf + (size_t)r * L_; g = g2; bb = b2; op = out2 + (size_t)r * L_; cols = L_;
    }
    float s = 0.f, s2 = 0.f;
    for (int i = threadIdx.x; i < cols; i += 256) {
        float v = rp[i]; s += v; s2 += v * v;
    }
    for (int off = 32; off; off >>= 1) {
        s  += __shfl_down(s,  off, 64);
        s2 += __shfl_down(s2, off, 64);
    }
    __shared__ float ps[4], ps2[4];
    __shared__ float smu, srstd;
    int wid = threadIdx.x >> 6, lid = threadIdx.x & 63;
    if (lid == 0) { ps[wid] = s; ps2[wid] = s2; }
    __syncthreads();
    if (threadIdx.x == 0) {
        float t = ps[0] + ps[1] + ps[2] + ps[3];
        float t2 = ps2[0] + ps2[1] + ps2[2] + ps2[3];
        float m = t / cols;
        float var = t2 / cols - m * m;
        smu = m; srstd = rsqrtf(var + 1e-5f);
    }
    __syncthreads();
    float mu = smu, rstd = srstd;
    for (int i = threadIdx.x; i < cols; i += 256) {
        float v = rp[i];
        op[i] = __float2bfloat16((v - mu) * rstd * g[i] + bb[i]);
    }
}

// -------- fused transpose+convert of all 4 weights: W(KxNc) -> Wt(NcxK) ----
__global__ __launch_bounds__(256) void tcvt4_kernel(const float* __restrict__ Wq,
                                                    const float* __restrict__ Wk,
                                                    const float* __restrict__ Wv,
                                                    const float* __restrict__ Wo,
                                                    bf16* __restrict__ wqt,
                                                    bf16* __restrict__ wkt,
                                                    bf16* __restrict__ wvt,
                                                    bf16* __restrict__ wot) {
    __shared__ ushort t[64][65];
    int y = blockIdx.y;
    const float* W; bf16* Wt; int K, ky;
    if (y < 16)      { W = Wq; Wt = wqt; K = 1024; ky = y; }
    else if (y < 28) { W = Wk; Wt = wkt; K = 768;  ky = y - 16; }
    else if (y < 40) { W = Wv; Wt = wvt; K = 768;  ky = y - 28; }
    else             { W = Wo; Wt = wot; K = 1024; ky = y - 40; }
    int k0 = ky * 64, n0 = blockIdx.x * 64;
    int tid = threadIdx.x;
#pragma unroll
    for (int i = 0; i < 16; i++) {
        int e = tid + i * 256;
        int r = e >> 6, c = e & 63;
        bf16 hv = __float2bfloat16(W[(size_t)(k0 + r) * D_ + n0 + c]);
        t[r][c] = *(ushort*)&hv;
    }
    __syncthreads();
#pragma unroll
    for (int i = 0; i < 16; i++) {
        int e = tid + i * 256;
        int r = e >> 6, c = e & 63;
        ushort uv = t[c][r];
        Wt[(size_t)(n0 + r) * K + k0 + c] = *(bf16*)&uv;
    }
}

// -------- shared MFMA GEMM body: 128x128 tile, BK=64, DMA staging ---------
// MODE 0: bf16 C = A@Bt^T + bias      MODE 1: f32 C = ... + bias + res
// MODE 2: V-scatter into pre-swizzled vT[b][h][d][n] layout
template <int MODE>
__device__ __forceinline__ void gemm_body(const ushort* __restrict__ Ap,
                                          const ushort* __restrict__ Bp,
                                          const float* __restrict__ bias,
                                          const float* __restrict__ res,
                                          void* __restrict__ Cout,
                                          int m0, int n0, int Ncols, int K,
                                          ushort* Ash, ushort* Bsh) {
    int tid = threadIdx.x;
    int w = tid >> 6, lane = tid & 63;
    int quad = lane >> 4, l15 = lane & 15;
    int wm = (w >> 1) * 64, wn = (w & 1) * 64;
    int lr8 = lane >> 3;          // row within 8-row DMA group
    int sc  = lane & 7;           // slot chunk
    int gc  = sc ^ lr8;           // global chunk this lane fetches (row&7 == lr8)
    f32x4 acc[4][4] = {};
    for (int kt = 0; kt < K; kt += 64) {
#pragma unroll
        for (int j = 0; j < 4; j++) {
            int rbase = w * 32 + j * 8;
            gld16(&Ap[(size_t)(m0 + rbase + lr8) * K + kt + gc * 8], &Ash[rbase * 64]);
            gld16(&Bp[(size_t)(n0 + rbase + lr8) * K + kt + gc * 8], &Bsh[rbase * 64]);
        }
        __syncthreads();
#pragma unroll
        for (int kh = 0; kh < 2; kh++) {
            bf16x8 af[4], bfr[4];
#pragma unroll
            for (int mt = 0; mt < 4; mt++)
                af[mt] = *(bf16x8*)&Ash[(wm + mt * 16 + l15) * 64 + (((kh * 4 + quad) ^ (l15 & 7)) * 8)];
#pragma unroll
            for (int nt = 0; nt < 4; nt++)
                bfr[nt] = *(bf16x8*)&Bsh[(wn + nt * 16 + l15) * 64 + (((kh * 4 + quad) ^ (l15 & 7)) * 8)];
#pragma unroll
            for (int mt = 0; mt < 4; mt++)
#pragma unroll
                for (int nt = 0; nt < 4; nt++)
                    acc[mt][nt] = __builtin_amdgcn_mfma_f32_16x16x32_bf16(af[mt], bfr[nt], acc[mt][nt], 0, 0, 0);
        }
        __syncthreads();
    }
#pragma unroll
    for (int mt = 0; mt < 4; mt++) {
#pragma unroll
        for (int nt = 0; nt < 4; nt++) {
#pragma unroll
            for (int reg = 0; reg < 4; reg++) {
                int row = m0 + wm + mt * 16 + quad * 4 + reg;
                int col = n0 + wn + nt * 16 + l15;
                float v = acc[mt][nt][reg] + bias[col];
                if (MODE == 1) {
                    v += res[(size_t)row * Ncols + col];
                    ((float*)Cout)[(size_t)row * Ncols + col] = v;
                } else if (MODE == 0) {
                    ((bf16*)Cout)[(size_t)row * Ncols + col] = __float2bfloat16(v);
                } else {
                    // V scatter: row = token (b,n), col = channel (h,d)
                    int b = row >> 8, n = row & 255;
                    int h = col >> 6, d = col & 63;
                    size_t addr = ((size_t)(b * 16 + h) * 64 + d) * 256
                                + (((n >> 3) ^ (d & 7)) * 8) + (n & 7);
                    ((bf16*)Cout)[addr] = __float2bfloat16(v);
                }
            }
        }
    }
}

// -------- fused Q/K/V projection: 512 + 128 + 128 blocks ------------------
__global__ __launch_bounds__(256) void qkv_gemm(const bf16* __restrict__ xn,
                                                const bf16* __restrict__ xfn,
                                                const bf16* __restrict__ wqt,
                                                const bf16* __restrict__ wkt,
                                                const bf16* __restrict__ wvt,
                                                const float* __restrict__ bq,
                                                const float* __restrict__ bk,
                                                const float* __restrict__ bv,
                                                bf16* __restrict__ q,
                                                bf16* __restrict__ kbuf,
                                                bf16* __restrict__ vT) {
    __shared__ ushort Ash[128 * 64];
    __shared__ ushort Bsh[128 * 64];
    int bid = blockIdx.x;
    if (bid < 512) {
        gemm_body<0>((const ushort*)xn, (const ushort*)wqt, bq, nullptr, q,
                     (bid >> 3) * 128, (bid & 7) * 128, D_, D_, Ash, Bsh);
    } else if (bid < 640) {
        int id = bid - 512;
        gemm_body<0>((const ushort*)xfn, (const ushort*)wkt, bk, nullptr, kbuf,
                     (id >> 3) * 128, (id & 7) * 128, D_, L_, Ash, Bsh);
    } else {
        int id = bid - 640;
        gemm_body<2>((const ushort*)xfn, (const ushort*)wvt, bv, nullptr, vT,
                     (id >> 3) * 128, (id & 7) * 128, D_, L_, Ash, Bsh);
    }
}

// -------- output projection + residual (f32 out) --------------------------
__global__ __launch_bounds__(256) void out_gemm(const bf16* __restrict__ a,
                                                const bf16* __restrict__ wot,
                                                const float* __restrict__ bout,
                                                const float* __restrict__ x,
                                                float* __restrict__ out) {
    __shared__ ushort Ash[128 * 64];
    __shared__ ushort Bsh[128 * 64];
    int bid = blockIdx.x;
    gemm_body<1>((const ushort*)a, (const ushort*)wot, bout, x, out,
                 (bid >> 3) * 128, (bid & 7) * 128, D_, D_, Ash, Bsh);
}

// -------- emb stage 1: partial dot over 256-k slab; grid (32 jc, 8 ks) -----
__global__ __launch_bounds__(256) void emb1_kernel(const float* __restrict__ emb,
                                                   const float* __restrict__ Wemb,
                                                   float* __restrict__ part) {
    __shared__ float se[8 * 256];
    __shared__ float red[16 * 8 * 64];
    int tid = threadIdx.x;
    int j0 = blockIdx.x * 64;
    int ks = blockIdx.y;
    int tx = tid & 15, ty = tid >> 4;
#pragma unroll
    for (int b = 0; b < 8; b++) {
        float xv = emb[b * TE_ + ks * 256 + tid];
        se[b * 256 + tid] = xv / (1.f + __expf(-xv));
    }
    __syncthreads();
    float acc[8][4] = {};
#pragma unroll 4
    for (int i = 0; i < 16; i++) {
        int e = ty + 16 * i;
        float4 wv = *(const float4*)&Wemb[(size_t)(ks * 256 + e) * 2048 + j0 + tx * 4];
#pragma unroll
        for (int b = 0; b < 8; b++) {
            float s = se[b * 256 + e];
            acc[b][0] += s * wv.x; acc[b][1] += s * wv.y;
            acc[b][2] += s * wv.z; acc[b][3] += s * wv.w;
        }
    }
#pragma unroll
    for (int b = 0; b < 8; b++)
#pragma unroll
        for (int m = 0; m < 4; m++)
            red[(ty * 8 + b) * 64 + tx * 4 + m] = acc[b][m];
    __syncthreads();
    for (int o = tid; o < 512; o += 256) {
        int b = o >> 6, jl = o & 63;
        float s = 0.f;
#pragma unroll
        for (int t2 = 0; t2 < 16; t2++) s += red[(t2 * 8 + b) * 64 + jl];
        part[((size_t)ks * 8 + b) * 2048 + j0 + jl] = s;
    }
}

// -------- emb stage 2: reduce 8 partials + bias ---------------------------
__global__ __launch_bounds__(256) void emb2_kernel(const float* __restrict__ part,
                                                   const float* __restrict__ bemb,
                                                   float* __restrict__ embo) {
    int o = blockIdx.x * 256 + threadIdx.x;
    int b = o >> 11, j = o & 2047;
    float s = bemb[j];
#pragma unroll
    for (int ks = 0; ks < 8; ks++) s += part[((size_t)ks * 8 + b) * 2048 + j];
    embo[o] = s;
}

// ---------------- MFMA attention: block = 64 q-rows x one (b,h) ----------
// All staging via global_load_lds DMA. V arrives pre-transposed+swizzled.
__global__ __launch_bounds__(256) void attn_mfma(const bf16* __restrict__ q,
                                                 const bf16* __restrict__ k,
                                                 const bf16* __restrict__ vT,
                                                 bf16* __restrict__ y) {
    __shared__ ushort KV[N_ * HD_];   // 32768 B: K rows, then Vt rows
    __shared__ ushort P[64 * N_];     // 32768 B: Q rows, then P rows
    int tid = threadIdx.x;
    int w = tid >> 6, lane = tid & 63;
    int quad = lane >> 4, l15 = lane & 15;
    int t0 = blockIdx.x * 64;
    int bh = blockIdx.y;
    int b = bh >> 4, h = bh & 15;

    const ushort* kp = (const ushort*)k;
    const ushort* qp = (const ushort*)q;
    const ushort* vp = (const ushort*)vT;
    int lr8 = lane >> 3, sc = lane & 7, gc = sc ^ lr8;

    // K DMA: 256 rows x 64, swizzled chunks
#pragma unroll
    for (int j = 0; j < 8; j++) {
        int rbase = w * 64 + j * 8;
        gld16(&kp[(size_t)(b * N_ + rbase + lr8) * D_ + h * 64 + gc * 8], &KV[rbase * 64]);
    }
    // Q DMA: 64 rows x 64
#pragma unroll
    for (int j = 0; j < 2; j++) {
        int rbase = w * 16 + j * 8;
        gld16(&qp[(size_t)(b * T_ + t0 + rbase + lr8) * D_ + h * 64 + gc * 8], &P[rbase * 64]);
    }
    __syncthreads();

    // S = Q K^T  (per wave: 16 q-rows x 256 ctx)
    int qrow = w * 16 + l15;
    bf16x8 aq[2];
#pragma unroll
    for (int kk = 0; kk < 2; kk++)
        aq[kk] = *(bf16x8*)&P[qrow * 64 + (((kk * 4 + quad) ^ (qrow & 7)) * 8)];
    f32x4 sf[16];
#pragma unroll
    for (int nt = 0; nt < 16; nt++) {
        int n = nt * 16 + l15;
        bf16x8 b0 = *(bf16x8*)&KV[n * 64 + (((0 + quad) ^ (n & 7)) * 8)];
        bf16x8 b1 = *(bf16x8*)&KV[n * 64 + (((4 + quad) ^ (n & 7)) * 8)];
        f32x4 z = {};
        f32x4 t = __builtin_amdgcn_mfma_f32_16x16x32_bf16(aq[0], b0, z, 0, 0, 0);
        sf[nt] = __builtin_amdgcn_mfma_f32_16x16x32_bf16(aq[1], b1, t, 0, 0, 0);
    }
    __syncthreads();   // all K reads done -> KV reusable for V

    // V DMA (identity copy of pre-swizzled vT) — latency hidden under softmax
    const ushort* vbase = vp + (size_t)(b * 16 + h) * 16384;
#pragma unroll
    for (int j = 0; j < 8; j++) {
        gld16(&vbase[(w * 8 + j) * 512 + lane * 8], &KV[(w * 8 + j) * 512]);
    }

    // one-shot softmax over N (rows = quad*4+reg)
    const float scale = 0.125f;
    float mx[4] = {-1e30f, -1e30f, -1e30f, -1e30f};
#pragma unroll
    for (int nt = 0; nt < 16; nt++)
#pragma unroll
        for (int reg = 0; reg < 4; reg++) mx[reg] = fmaxf(mx[reg], sf[nt][reg]);
#pragma unroll
    for (int off = 1; off < 16; off <<= 1)
#pragma unroll
        for (int reg = 0; reg < 4; reg++)
            mx[reg] = fmaxf(mx[reg], __shfl_xor(mx[reg], off, 64));
    float sm[4] = {0.f, 0.f, 0.f, 0.f};
#pragma unroll
    for (int nt = 0; nt < 16; nt++)
#pragma unroll
        for (int reg = 0; reg < 4; reg++) {
            float e = __expf((sf[nt][reg] - mx[reg]) * scale);
            sf[nt][reg] = e;
            sm[reg] += e;
        }
#pragma unroll
    for (int off = 1; off < 16; off <<= 1)
#pragma unroll
        for (int reg = 0; reg < 4; reg++)
            sm[reg] += __shfl_xor(sm[reg], off, 64);
    float inv[4];
#pragma unroll
    for (int reg = 0; reg < 4; reg++) inv[reg] = 1.f / sm[reg];

    // write P (bf16, A-operand layout w/ swizzle) — own-wave rows only
#pragma unroll
    for (int nt = 0; nt < 16; nt++)
#pragma unroll
        for (int reg = 0; reg < 4; reg++) {
            int r = w * 16 + quad * 4 + reg;
            int colc = nt * 2 + (l15 >> 3);
            int addr = r * 256 + ((colc ^ (r & 7)) * 8) + (l15 & 7);
            bf16 hv = __float2bfloat16(sf[nt][reg]);
            P[addr] = *(ushort*)&hv;
        }
    __syncthreads();   // drains V DMA (vmcnt) + P writes visible

    // O = P @ V : per wave 16 rows x 64 d, K-dim = 256
    f32x4 of[4] = {};
    int prow = w * 16 + l15;
#pragma unroll
    for (int kk = 0; kk < 8; kk++) {
        bf16x8 ap = *(bf16x8*)&P[prow * 256 + (((kk * 4 + quad) ^ (prow & 7)) * 8)];
#pragma unroll
        for (int dt = 0; dt < 4; dt++) {
            int d = dt * 16 + l15;
            bf16x8 bv = *(bf16x8*)&KV[d * 256 + (((kk * 4 + quad) ^ (d & 7)) * 8)];
            of[dt] = __builtin_amdgcn_mfma_f32_16x16x32_bf16(ap, bv, of[dt], 0, 0, 0);
        }
    }
#pragma unroll
    for (int dt = 0; dt < 4; dt++)
#pragma unroll
        for (int reg = 0; reg < 4; reg++) {
            int r = t0 + w * 16 + quad * 4 + reg;
            y[((size_t)(b * T_ + r) * D_) + h * 64 + dt * 16 + l15] =
                __float2bfloat16(of[dt][reg] * inv[reg]);
        }
}

// ------- stylization: LN(y)*(1+scale)+shift, then silu; y bf16 -----------
__global__ __launch_bounds__(256) void styl_kernel(const bf16* __restrict__ y,
                                                   const float* __restrict__ g,
                                                   const float* __restrict__ bb,
                                                   const float* __restrict__ embo,
                                                   bf16* __restrict__ a) {
    int row = blockIdx.x;
    int b = row >> 10;
    const bf16* rp = y + (size_t)row * D_;
    float s = 0.f, s2 = 0.f;
    for (int i = threadIdx.x; i < D_; i += 256) {
        float v = __bfloat162float(rp[i]); s += v; s2 += v * v;
    }
    for (int off = 32; off; off >>= 1) {
        s  += __shfl_down(s,  off, 64);
        s2 += __shfl_down(s2, off, 64);
    }
    __shared__ float ps[4], ps2[4];
    __shared__ float smu, srstd;
    int wid = threadIdx.x >> 6, lid = threadIdx.x & 63;
    if (lid == 0) { ps[wid] = s; ps2[wid] = s2; }
    __syncthreads();
    if (threadIdx.x == 0) {
        float t = ps[0] + ps[1] + ps[2] + ps[3];
        float t2 = ps2[0] + ps2[1] + ps2[2] + ps2[3];
        float m = t / D_;
        float var = t2 / D_ - m * m;
        smu = m; srstd = rsqrtf(var + 1e-5f);
    }
    __syncthreads();
    float mu = smu, rstd = srstd;
    for (int i = threadIdx.x; i < D_; i += 256) {
        float v = __bfloat162float(rp[i]);
        float nrm = (v - mu) * rstd * g[i] + bb[i];
        float sc = embo[b * 2048 + i];
        float sh = embo[b * 2048 + 1024 + i];
        float hh = nrm * (1.f + sc) + sh;
        float sig = 1.f / (1.f + __expf(-hh));
        a[(size_t)row * D_ + i] = __float2bfloat16(hh * sig);
    }
}

extern "C" void kernel_launch(void* const* d_in, const int* in_sizes, int n_in,
                              void* d_out, int out_size, void* d_ws, size_t ws_size,
                              hipStream_t stream) {
    const float* x    = (const float*)d_in[0];
    const float* xf   = (const float*)d_in[1];
    const float* emb  = (const float*)d_in[2];
    const float* ln_g = (const float*)d_in[3];
    const float* ln_b = (const float*)d_in[4];
    const float* cln_g= (const float*)d_in[5];
    const float* cln_b= (const float*)d_in[6];
    const float* Wq   = (const float*)d_in[7];
    const float* bq   = (const float*)d_in[8];
    const float* Wk   = (const float*)d_in[9];
    const float* bk   = (const float*)d_in[10];
    const float* Wv   = (const float*)d_in[11];
    const float* bv   = (const float*)d_in[12];
    const float* sln_g= (const float*)d_in[13];
    const float* sln_b= (const float*)d_in[14];
    const float* Wemb = (const float*)d_in[15];
    const float* bemb = (const float*)d_in[16];
    const float* Wout = (const float*)d_in[17];
    const float* bout = (const float*)d_in[18];
    float* out = (float*)d_out;

    char* wsp = (char*)d_ws;
    bf16*  xn   = (bf16*)(wsp);                   // 8192x1024 bf16 16MB (reused as y)
    bf16*  xfn  = (bf16*)(wsp + 16777216);        // 2048x768  bf16  3MB
    bf16*  q    = (bf16*)(wsp + 19922944);        // 8192x1024 bf16 16MB (reused as a)
    bf16*  kbuf = (bf16*)(wsp + 36700160);        // 2048x1024 bf16  4MB
    bf16*  vT   = (bf16*)(wsp + 40894464);        // [b][h][64][256] bf16 4MB pre-swizzled
    float* embo = (float*)(wsp + 45088768);       // 8x2048    f32  64KB
    bf16*  wqt  = (bf16*)(wsp + 45154304);        // 1024x1024 bf16  2MB
    bf16*  wkt  = (bf16*)(wsp + 47251456);        // 1024x768  bf16 1.5MB
    bf16*  wvt  = (bf16*)(wsp + 48824320);        // 1024x768  bf16 1.5MB
    bf16*  wot  = (bf16*)(wsp + 50397184);        // 1024x1024 bf16  2MB
    float* part = (float*)(wsp + 52494336);       // 8x8x2048  f32  512KB
    bf16*  ybuf = xn;   // alias: xn dead after Q-proj
    bf16*  abuf = q;    // alias: q dead after attn

    ln_both_kernel<<<B_ * T_ + B_ * N_, 256, 0, stream>>>(x, xf, ln_g, ln_b, cln_g, cln_b, xn, xfn);

    tcvt4_kernel<<<dim3(16, 56), 256, 0, stream>>>(Wq, Wk, Wv, Wout, wqt, wkt, wvt, wot);

    emb1_kernel<<<dim3(32, 8), 256, 0, stream>>>(emb, Wemb, part);
    emb2_kernel<<<64, 256, 0, stream>>>(part, bemb, embo);

    qkv_gemm<<<768, 256, 0, stream>>>(xn, xfn, wqt, wkt, wvt, bq, bk, bv, q, kbuf, vT);

    attn_mfma<<<dim3(16, 128), 256, 0, stream>>>(q, kbuf, vT, ybuf);

    styl_kernel<<<B_ * T_, 256, 0, stream>>>(ybuf, sln_g, sln_b, embo, abuf);

    out_gemm<<<512, 256, 0, stream>>>(abuf, wot, bout, x, out);
}

// Round 6
// 258.492 us; speedup vs baseline: 4.9881x; 1.0731x over previous
//
#include <hip/hip_runtime.h>
#include <hip/hip_bf16.h>

typedef __hip_bfloat16 bf16;
typedef unsigned short ushort;
typedef __attribute__((ext_vector_type(8))) short bf16x8;
typedef __attribute__((ext_vector_type(4))) float f32x4;

#define B_ 8
#define T_ 1024
#define D_ 1024
#define N_ 256
#define L_ 768
#define H_ 16
#define HD_ 64
#define TE_ 2048

__device__ __forceinline__ void gld16(const void* g, void* l) {
    __builtin_amdgcn_global_load_lds((const __attribute__((address_space(1))) void*)g,
                                     (__attribute__((address_space(3))) void*)l,
                                     16, 0, 0);
}

__device__ __forceinline__ float bitf(unsigned u) { return __uint_as_float(u); }

// ------- fused LayerNorm, vectorized 4 cols/thread ------------------------
__global__ __launch_bounds__(256) void ln_both_kernel(const float* __restrict__ x,
                                                      const float* __restrict__ xf,
                                                      const float* __restrict__ g1,
                                                      const float* __restrict__ b1,
                                                      const float* __restrict__ g2,
                                                      const float* __restrict__ b2,
                                                      bf16* __restrict__ out1,
                                                      bf16* __restrict__ out2) {
    int row = blockIdx.x;
    int tid = threadIdx.x;
    const float *rp, *g, *bb; bf16* op; int cols;
    if (row < B_ * T_) {
        rp = x + (size_t)row * D_; g = g1; bb = b1; op = out1 + (size_t)row * D_; cols = D_;
    } else {
        int r = row - B_ * T_;
        rp = xf + (size_t)r * L_; g = g2; bb = b2; op = out2 + (size_t)r * L_; cols = L_;
    }
    bool act = tid * 4 < cols;
    float4 v = act ? *(const float4*)&rp[tid * 4] : make_float4(0.f, 0.f, 0.f, 0.f);
    float s = v.x + v.y + v.z + v.w;
    float s2 = v.x * v.x + v.y * v.y + v.z * v.z + v.w * v.w;
    for (int off = 32; off; off >>= 1) {
        s  += __shfl_down(s,  off, 64);
        s2 += __shfl_down(s2, off, 64);
    }
    __shared__ float ps[4], ps2[4];
    __shared__ float smu, srstd;
    int wid = tid >> 6, lid = tid & 63;
    if (lid == 0) { ps[wid] = s; ps2[wid] = s2; }
    __syncthreads();
    if (tid == 0) {
        float t = ps[0] + ps[1] + ps[2] + ps[3];
        float t2 = ps2[0] + ps2[1] + ps2[2] + ps2[3];
        float m = t / cols;
        float var = t2 / cols - m * m;
        smu = m; srstd = rsqrtf(var + 1e-5f);
    }
    __syncthreads();
    if (!act) return;
    float mu = smu, rstd = srstd;
    float4 gv = *(const float4*)&g[tid * 4];
    float4 bv = *(const float4*)&bb[tid * 4];
    float o0 = (v.x - mu) * rstd * gv.x + bv.x;
    float o1 = (v.y - mu) * rstd * gv.y + bv.y;
    float o2 = (v.z - mu) * rstd * gv.z + bv.z;
    float o3 = (v.w - mu) * rstd * gv.w + bv.w;
    ushort4 uo;
    bf16 h0 = __float2bfloat16(o0); uo.x = *(ushort*)&h0;
    bf16 h1 = __float2bfloat16(o1); uo.y = *(ushort*)&h1;
    bf16 h2 = __float2bfloat16(o2); uo.z = *(ushort*)&h2;
    bf16 h3 = __float2bfloat16(o3); uo.w = *(ushort*)&h3;
    *(ushort4*)&op[tid * 4] = uo;
}

// -------- fused transpose+convert of all 4 weights: W(KxNc) -> Wt(NcxK) ----
__global__ __launch_bounds__(256) void tcvt4_kernel(const float* __restrict__ Wq,
                                                    const float* __restrict__ Wk,
                                                    const float* __restrict__ Wv,
                                                    const float* __restrict__ Wo,
                                                    bf16* __restrict__ wqt,
                                                    bf16* __restrict__ wkt,
                                                    bf16* __restrict__ wvt,
                                                    bf16* __restrict__ wot) {
    __shared__ ushort t[64][65];
    int y = blockIdx.y;
    const float* W; bf16* Wt; int K, ky;
    if (y < 16)      { W = Wq; Wt = wqt; K = 1024; ky = y; }
    else if (y < 28) { W = Wk; Wt = wkt; K = 768;  ky = y - 16; }
    else if (y < 40) { W = Wv; Wt = wvt; K = 768;  ky = y - 28; }
    else             { W = Wo; Wt = wot; K = 1024; ky = y - 40; }
    int k0 = ky * 64, n0 = blockIdx.x * 64;
    int tid = threadIdx.x;
#pragma unroll
    for (int i = 0; i < 16; i++) {
        int e = tid + i * 256;
        int r = e >> 6, c = e & 63;
        bf16 hv = __float2bfloat16(W[(size_t)(k0 + r) * D_ + n0 + c]);
        t[r][c] = *(ushort*)&hv;
    }
    __syncthreads();
#pragma unroll
    for (int i = 0; i < 16; i++) {
        int e = tid + i * 256;
        int r = e >> 6, c = e & 63;
        ushort uv = t[c][r];
        Wt[(size_t)(n0 + r) * K + k0 + c] = *(bf16*)&uv;
    }
}

// -------- shared MFMA GEMM body: 128x128 tile, BK=64, DMA staging ---------
template <int MODE>
__device__ __forceinline__ void gemm_body(const ushort* __restrict__ Ap,
                                          const ushort* __restrict__ Bp,
                                          const float* __restrict__ bias,
                                          const float* __restrict__ res,
                                          void* __restrict__ Cout,
                                          int m0, int n0, int Ncols, int K,
                                          ushort* Ash, ushort* Bsh) {
    int tid = threadIdx.x;
    int w = tid >> 6, lane = tid & 63;
    int quad = lane >> 4, l15 = lane & 15;
    int wm = (w >> 1) * 64, wn = (w & 1) * 64;
    int lr8 = lane >> 3;
    int sc  = lane & 7;
    int gc  = sc ^ lr8;
    f32x4 acc[4][4] = {};
    for (int kt = 0; kt < K; kt += 64) {
#pragma unroll
        for (int j = 0; j < 4; j++) {
            int rbase = w * 32 + j * 8;
            gld16(&Ap[(size_t)(m0 + rbase + lr8) * K + kt + gc * 8], &Ash[rbase * 64]);
            gld16(&Bp[(size_t)(n0 + rbase + lr8) * K + kt + gc * 8], &Bsh[rbase * 64]);
        }
        __syncthreads();
#pragma unroll
        for (int kh = 0; kh < 2; kh++) {
            bf16x8 af[4], bfr[4];
#pragma unroll
            for (int mt = 0; mt < 4; mt++)
                af[mt] = *(bf16x8*)&Ash[(wm + mt * 16 + l15) * 64 + (((kh * 4 + quad) ^ (l15 & 7)) * 8)];
#pragma unroll
            for (int nt = 0; nt < 4; nt++)
                bfr[nt] = *(bf16x8*)&Bsh[(wn + nt * 16 + l15) * 64 + (((kh * 4 + quad) ^ (l15 & 7)) * 8)];
#pragma unroll
            for (int mt = 0; mt < 4; mt++)
#pragma unroll
                for (int nt = 0; nt < 4; nt++)
                    acc[mt][nt] = __builtin_amdgcn_mfma_f32_16x16x32_bf16(af[mt], bfr[nt], acc[mt][nt], 0, 0, 0);
        }
        __syncthreads();
    }
#pragma unroll
    for (int mt = 0; mt < 4; mt++) {
#pragma unroll
        for (int nt = 0; nt < 4; nt++) {
#pragma unroll
            for (int reg = 0; reg < 4; reg++) {
                int row = m0 + wm + mt * 16 + quad * 4 + reg;
                int col = n0 + wn + nt * 16 + l15;
                float v = acc[mt][nt][reg] + bias[col];
                if (MODE == 1) {
                    v += res[(size_t)row * Ncols + col];
                    ((float*)Cout)[(size_t)row * Ncols + col] = v;
                } else if (MODE == 0) {
                    ((bf16*)Cout)[(size_t)row * Ncols + col] = __float2bfloat16(v);
                } else {
                    int b = row >> 8, n = row & 255;
                    int h = col >> 6, d = col & 63;
                    size_t addr = ((size_t)(b * 16 + h) * 64 + d) * 256
                                + (((n >> 3) ^ (d & 7)) * 8) + (n & 7);
                    ((bf16*)Cout)[addr] = __float2bfloat16(v);
                }
            }
        }
    }
}

// -------- fused Q/K/V projection. XCD-local m mapping: m = id % Mb --------
__global__ __launch_bounds__(256) void qkv_gemm(const bf16* __restrict__ xn,
                                                const bf16* __restrict__ xfn,
                                                const bf16* __restrict__ wqt,
                                                const bf16* __restrict__ wkt,
                                                const bf16* __restrict__ wvt,
                                                const float* __restrict__ bq,
                                                const float* __restrict__ bk,
                                                const float* __restrict__ bv,
                                                bf16* __restrict__ q,
                                                bf16* __restrict__ kbuf,
                                                bf16* __restrict__ vT) {
    __shared__ ushort Ash[128 * 64];
    __shared__ ushort Bsh[128 * 64];
    int bid = blockIdx.x;
    if (bid < 512) {
        // m = bid & 63 -> same-m blocks share bid%8 -> same XCD L2 holds A-panel
        gemm_body<0>((const ushort*)xn, (const ushort*)wqt, bq, nullptr, q,
                     (bid & 63) * 128, (bid >> 6) * 128, D_, D_, Ash, Bsh);
    } else if (bid < 640) {
        int id = bid - 512;
        gemm_body<0>((const ushort*)xfn, (const ushort*)wkt, bk, nullptr, kbuf,
                     (id & 15) * 128, (id >> 4) * 128, D_, L_, Ash, Bsh);
    } else {
        int id = bid - 640;
        gemm_body<2>((const ushort*)xfn, (const ushort*)wvt, bv, nullptr, vT,
                     (id & 15) * 128, (id >> 4) * 128, D_, L_, Ash, Bsh);
    }
}

// -------- output projection + residual (f32 out) --------------------------
__global__ __launch_bounds__(256) void out_gemm(const bf16* __restrict__ a,
                                                const bf16* __restrict__ wot,
                                                const float* __restrict__ bout,
                                                const float* __restrict__ x,
                                                float* __restrict__ out) {
    __shared__ ushort Ash[128 * 64];
    __shared__ ushort Bsh[128 * 64];
    int bid = blockIdx.x;
    gemm_body<1>((const ushort*)a, (const ushort*)wot, bout, x, out,
                 (bid & 63) * 128, (bid >> 6) * 128, D_, D_, Ash, Bsh);
}

// -------- emb stage 1: partial dot over 256-k slab; grid (32 jc, 8 ks) -----
__global__ __launch_bounds__(256) void emb1_kernel(const float* __restrict__ emb,
                                                   const float* __restrict__ Wemb,
                                                   float* __restrict__ part) {
    __shared__ float se[8 * 256];
    __shared__ float red[16 * 8 * 64];
    int tid = threadIdx.x;
    int j0 = blockIdx.x * 64;
    int ks = blockIdx.y;
    int tx = tid & 15, ty = tid >> 4;
#pragma unroll
    for (int b = 0; b < 8; b++) {
        float xv = emb[b * TE_ + ks * 256 + tid];
        se[b * 256 + tid] = xv / (1.f + __expf(-xv));
    }
    __syncthreads();
    float acc[8][4] = {};
#pragma unroll 4
    for (int i = 0; i < 16; i++) {
        int e = ty + 16 * i;
        float4 wv = *(const float4*)&Wemb[(size_t)(ks * 256 + e) * 2048 + j0 + tx * 4];
#pragma unroll
        for (int b = 0; b < 8; b++) {
            float s = se[b * 256 + e];
            acc[b][0] += s * wv.x; acc[b][1] += s * wv.y;
            acc[b][2] += s * wv.z; acc[b][3] += s * wv.w;
        }
    }
#pragma unroll
    for (int b = 0; b < 8; b++)
#pragma unroll
        for (int m = 0; m < 4; m++)
            red[(ty * 8 + b) * 64 + tx * 4 + m] = acc[b][m];
    __syncthreads();
    for (int o = tid; o < 512; o += 256) {
        int b = o >> 6, jl = o & 63;
        float s = 0.f;
#pragma unroll
        for (int t2 = 0; t2 < 16; t2++) s += red[(t2 * 8 + b) * 64 + jl];
        part[((size_t)ks * 8 + b) * 2048 + j0 + jl] = s;
    }
}

// -------- emb stage 2: reduce 8 partials + bias ---------------------------
__global__ __launch_bounds__(256) void emb2_kernel(const float* __restrict__ part,
                                                   const float* __restrict__ bemb,
                                                   float* __restrict__ embo) {
    int o = blockIdx.x * 256 + threadIdx.x;
    int b = o >> 11, j = o & 2047;
    float s = bemb[j];
#pragma unroll
    for (int ks = 0; ks < 8; ks++) s += part[((size_t)ks * 8 + b) * 2048 + j];
    embo[o] = s;
}

// ---------------- MFMA attention: block = 64 q-rows x one (b,h) ----------
__global__ __launch_bounds__(256) void attn_mfma(const bf16* __restrict__ q,
                                                 const bf16* __restrict__ k,
                                                 const bf16* __restrict__ vT,
                                                 bf16* __restrict__ y) {
    __shared__ ushort KV[N_ * HD_];
    __shared__ ushort P[64 * N_];
    int tid = threadIdx.x;
    int w = tid >> 6, lane = tid & 63;
    int quad = lane >> 4, l15 = lane & 15;
    int t0 = blockIdx.x * 64;
    int bh = blockIdx.y;
    int b = bh >> 4, h = bh & 15;

    const ushort* kp = (const ushort*)k;
    const ushort* qp = (const ushort*)q;
    const ushort* vp = (const ushort*)vT;
    int lr8 = lane >> 3, sc = lane & 7, gc = sc ^ lr8;

#pragma unroll
    for (int j = 0; j < 8; j++) {
        int rbase = w * 64 + j * 8;
        gld16(&kp[(size_t)(b * N_ + rbase + lr8) * D_ + h * 64 + gc * 8], &KV[rbase * 64]);
    }
#pragma unroll
    for (int j = 0; j < 2; j++) {
        int rbase = w * 16 + j * 8;
        gld16(&qp[(size_t)(b * T_ + t0 + rbase + lr8) * D_ + h * 64 + gc * 8], &P[rbase * 64]);
    }
    __syncthreads();

    int qrow = w * 16 + l15;
    bf16x8 aq[2];
#pragma unroll
    for (int kk = 0; kk < 2; kk++)
        aq[kk] = *(bf16x8*)&P[qrow * 64 + (((kk * 4 + quad) ^ (qrow & 7)) * 8)];
    f32x4 sf[16];
#pragma unroll
    for (int nt = 0; nt < 16; nt++) {
        int n = nt * 16 + l15;
        bf16x8 b0 = *(bf16x8*)&KV[n * 64 + (((0 + quad) ^ (n & 7)) * 8)];
        bf16x8 b1 = *(bf16x8*)&KV[n * 64 + (((4 + quad) ^ (n & 7)) * 8)];
        f32x4 z = {};
        f32x4 t = __builtin_amdgcn_mfma_f32_16x16x32_bf16(aq[0], b0, z, 0, 0, 0);
        sf[nt] = __builtin_amdgcn_mfma_f32_16x16x32_bf16(aq[1], b1, t, 0, 0, 0);
    }
    __syncthreads();

    const ushort* vbase = vp + (size_t)(b * 16 + h) * 16384;
#pragma unroll
    for (int j = 0; j < 8; j++) {
        gld16(&vbase[(w * 8 + j) * 512 + lane * 8], &KV[(w * 8 + j) * 512]);
    }

    const float scale = 0.125f;
    float mx[4] = {-1e30f, -1e30f, -1e30f, -1e30f};
#pragma unroll
    for (int nt = 0; nt < 16; nt++)
#pragma unroll
        for (int reg = 0; reg < 4; reg++) mx[reg] = fmaxf(mx[reg], sf[nt][reg]);
#pragma unroll
    for (int off = 1; off < 16; off <<= 1)
#pragma unroll
        for (int reg = 0; reg < 4; reg++)
            mx[reg] = fmaxf(mx[reg], __shfl_xor(mx[reg], off, 64));
    float sm[4] = {0.f, 0.f, 0.f, 0.f};
#pragma unroll
    for (int nt = 0; nt < 16; nt++)
#pragma unroll
        for (int reg = 0; reg < 4; reg++) {
            float e = __expf((sf[nt][reg] - mx[reg]) * scale);
            sf[nt][reg] = e;
            sm[reg] += e;
        }
#pragma unroll
    for (int off = 1; off < 16; off <<= 1)
#pragma unroll
        for (int reg = 0; reg < 4; reg++)
            sm[reg] += __shfl_xor(sm[reg], off, 64);
    float inv[4];
#pragma unroll
    for (int reg = 0; reg < 4; reg++) inv[reg] = 1.f / sm[reg];

#pragma unroll
    for (int nt = 0; nt < 16; nt++)
#pragma unroll
        for (int reg = 0; reg < 4; reg++) {
            int r = w * 16 + quad * 4 + reg;
            int colc = nt * 2 + (l15 >> 3);
            int addr = r * 256 + ((colc ^ (r & 7)) * 8) + (l15 & 7);
            bf16 hv = __float2bfloat16(sf[nt][reg]);
            P[addr] = *(ushort*)&hv;
        }
    __syncthreads();

    f32x4 of[4] = {};
    int prow = w * 16 + l15;
#pragma unroll
    for (int kk = 0; kk < 8; kk++) {
        bf16x8 ap = *(bf16x8*)&P[prow * 256 + (((kk * 4 + quad) ^ (prow & 7)) * 8)];
#pragma unroll
        for (int dt = 0; dt < 4; dt++) {
            int d = dt * 16 + l15;
            bf16x8 bv = *(bf16x8*)&KV[d * 256 + (((kk * 4 + quad) ^ (d & 7)) * 8)];
            of[dt] = __builtin_amdgcn_mfma_f32_16x16x32_bf16(ap, bv, of[dt], 0, 0, 0);
        }
    }
#pragma unroll
    for (int dt = 0; dt < 4; dt++)
#pragma unroll
        for (int reg = 0; reg < 4; reg++) {
            int r = t0 + w * 16 + quad * 4 + reg;
            y[((size_t)(b * T_ + r) * D_) + h * 64 + dt * 16 + l15] =
                __float2bfloat16(of[dt][reg] * inv[reg]);
        }
}

// ------- stylization, vectorized 4 cols/thread ----------------------------
__global__ __launch_bounds__(256) void styl_kernel(const bf16* __restrict__ y,
                                                   const float* __restrict__ g,
                                                   const float* __restrict__ bb,
                                                   const float* __restrict__ embo,
                                                   bf16* __restrict__ a) {
    int row = blockIdx.x;
    int b = row >> 10;
    int tid = threadIdx.x;
    const ushort* rp = (const ushort*)(y + (size_t)row * D_);
    ushort4 uy = *(const ushort4*)&rp[tid * 4];
    float v0 = bitf((unsigned)uy.x << 16), v1 = bitf((unsigned)uy.y << 16);
    float v2 = bitf((unsigned)uy.z << 16), v3 = bitf((unsigned)uy.w << 16);
    float s = v0 + v1 + v2 + v3;
    float s2 = v0 * v0 + v1 * v1 + v2 * v2 + v3 * v3;
    for (int off = 32; off; off >>= 1) {
        s  += __shfl_down(s,  off, 64);
        s2 += __shfl_down(s2, off, 64);
    }
    __shared__ float ps[4], ps2[4];
    __shared__ float smu, srstd;
    int wid = tid >> 6, lid = tid & 63;
    if (lid == 0) { ps[wid] = s; ps2[wid] = s2; }
    __syncthreads();
    if (tid == 0) {
        float t = ps[0] + ps[1] + ps[2] + ps[3];
        float t2 = ps2[0] + ps2[1] + ps2[2] + ps2[3];
        float m = t / D_;
        float var = t2 / D_ - m * m;
        smu = m; srstd = rsqrtf(var + 1e-5f);
    }
    __syncthreads();
    float mu = smu, rstd = srstd;
    float4 gv = *(const float4*)&g[tid * 4];
    float4 bv = *(const float4*)&bb[tid * 4];
    float4 scv = *(const float4*)&embo[b * 2048 + tid * 4];
    float4 shv = *(const float4*)&embo[b * 2048 + 1024 + tid * 4];
    float n0 = (v0 - mu) * rstd * gv.x + bv.x;
    float n1 = (v1 - mu) * rstd * gv.y + bv.y;
    float n2 = (v2 - mu) * rstd * gv.z + bv.z;
    float n3 = (v3 - mu) * rstd * gv.w + bv.w;
    float h0 = n0 * (1.f + scv.x) + shv.x;
    float h1 = n1 * (1.f + scv.y) + shv.y;
    float h2 = n2 * (1.f + scv.z) + shv.z;
    float h3 = n3 * (1.f + scv.w) + shv.w;
    h0 = h0 / (1.f + __expf(-h0));
    h1 = h1 / (1.f + __expf(-h1));
    h2 = h2 / (1.f + __expf(-h2));
    h3 = h3 / (1.f + __expf(-h3));
    ushort4 uo;
    bf16 t0 = __float2bfloat16(h0); uo.x = *(ushort*)&t0;
    bf16 t1 = __float2bfloat16(h1); uo.y = *(ushort*)&t1;
    bf16 t2 = __float2bfloat16(h2); uo.z = *(ushort*)&t2;
    bf16 t3 = __float2bfloat16(h3); uo.w = *(ushort*)&t3;
    *(ushort4*)&((ushort*)a)[(size_t)row * D_ + tid * 4] = uo;
}

extern "C" void kernel_launch(void* const* d_in, const int* in_sizes, int n_in,
                              void* d_out, int out_size, void* d_ws, size_t ws_size,
                              hipStream_t stream) {
    const float* x    = (const float*)d_in[0];
    const float* xf   = (const float*)d_in[1];
    const float* emb  = (const float*)d_in[2];
    const float* ln_g = (const float*)d_in[3];
    const float* ln_b = (const float*)d_in[4];
    const float* cln_g= (const float*)d_in[5];
    const float* cln_b= (const float*)d_in[6];
    const float* Wq   = (const float*)d_in[7];
    const float* bq   = (const float*)d_in[8];
    const float* Wk   = (const float*)d_in[9];
    const float* bk   = (const float*)d_in[10];
    const float* Wv   = (const float*)d_in[11];
    const float* bv   = (const float*)d_in[12];
    const float* sln_g= (const float*)d_in[13];
    const float* sln_b= (const float*)d_in[14];
    const float* Wemb = (const float*)d_in[15];
    const float* bemb = (const float*)d_in[16];
    const float* Wout = (const float*)d_in[17];
    const float* bout = (const float*)d_in[18];
    float* out = (float*)d_out;

    char* wsp = (char*)d_ws;
    bf16*  xn   = (bf16*)(wsp);                   // 8192x1024 bf16 16MB (reused as y)
    bf16*  xfn  = (bf16*)(wsp + 16777216);        // 2048x768  bf16  3MB
    bf16*  q    = (bf16*)(wsp + 19922944);        // 8192x1024 bf16 16MB (reused as a)
    bf16*  kbuf = (bf16*)(wsp + 36700160);        // 2048x1024 bf16  4MB
    bf16*  vT   = (bf16*)(wsp + 40894464);        // [b][h][64][256] bf16 4MB pre-swizzled
    float* embo = (float*)(wsp + 45088768);       // 8x2048    f32  64KB
    bf16*  wqt  = (bf16*)(wsp + 45154304);        // 1024x1024 bf16  2MB
    bf16*  wkt  = (bf16*)(wsp + 47251456);        // 1024x768  bf16 1.5MB
    bf16*  wvt  = (bf16*)(wsp + 48824320);        // 1024x768  bf16 1.5MB
    bf16*  wot  = (bf16*)(wsp + 50397184);        // 1024x1024 bf16  2MB
    float* part = (float*)(wsp + 52494336);       // 8x8x2048  f32  512KB
    bf16*  ybuf = xn;
    bf16*  abuf = q;

    ln_both_kernel<<<B_ * T_ + B_ * N_, 256, 0, stream>>>(x, xf, ln_g, ln_b, cln_g, cln_b, xn, xfn);

    tcvt4_kernel<<<dim3(16, 56), 256, 0, stream>>>(Wq, Wk, Wv, Wout, wqt, wkt, wvt, wot);

    emb1_kernel<<<dim3(32, 8), 256, 0, stream>>>(emb, Wemb, part);
    emb2_kernel<<<64, 256, 0, stream>>>(part, bemb, embo);

    qkv_gemm<<<768, 256, 0, stream>>>(xn, xfn, wqt, wkt, wvt, bq, bk, bv, q, kbuf, vT);

    attn_mfma<<<dim3(16, 128), 256, 0, stream>>>(q, kbuf, vT, ybuf);

    styl_kernel<<<B_ * T_, 256, 0, stream>>>(ybuf, sln_g, sln_b, embo, abuf);

    out_gemm<<<512, 256, 0, stream>>>(abuf, wot, bout, x, out);
}

// Round 7
// 255.751 us; speedup vs baseline: 5.0415x; 1.0107x over previous
//
#include <hip/hip_runtime.h>
#include <hip/hip_bf16.h>

typedef __hip_bfloat16 bf16;
typedef unsigned short ushort;
typedef __attribute__((ext_vector_type(8))) short bf16x8;
typedef __attribute__((ext_vector_type(4))) float f32x4;

#define B_ 8
#define T_ 1024
#define D_ 1024
#define N_ 256
#define L_ 768
#define H_ 16
#define HD_ 64
#define TE_ 2048

__device__ __forceinline__ void gld16(const void* g, void* l) {
    __builtin_amdgcn_global_load_lds((const __attribute__((address_space(1))) void*)g,
                                     (__attribute__((address_space(3))) void*)l,
                                     16, 0, 0);
}

__device__ __forceinline__ float bitf(unsigned u) { return __uint_as_float(u); }

// ===== prep: fused LN(x)+LN(xf) [0,10240) | tcvt4 [10240,11136) | emb1 [11136,11392)
__global__ __launch_bounds__(256) void prep_kernel(
        const float* __restrict__ x, const float* __restrict__ xf,
        const float* __restrict__ g1, const float* __restrict__ b1,
        const float* __restrict__ g2, const float* __restrict__ b2,
        const float* __restrict__ Wq, const float* __restrict__ Wk,
        const float* __restrict__ Wv, const float* __restrict__ Wo,
        const float* __restrict__ emb, const float* __restrict__ Wemb,
        bf16* __restrict__ out1, bf16* __restrict__ out2,
        bf16* __restrict__ wqt, bf16* __restrict__ wkt,
        bf16* __restrict__ wvt, bf16* __restrict__ wot,
        float* __restrict__ part) {
    __shared__ __align__(16) char smem[16384];
    int bid = blockIdx.x;
    int tid = threadIdx.x;
    if (bid < 10240) {
        // ---------------- LayerNorm, vectorized 4 cols/thread -------------
        const float *rp, *g, *bb; bf16* op; int cols;
        if (bid < B_ * T_) {
            rp = x + (size_t)bid * D_; g = g1; bb = b1; op = out1 + (size_t)bid * D_; cols = D_;
        } else {
            int r = bid - B_ * T_;
            rp = xf + (size_t)r * L_; g = g2; bb = b2; op = out2 + (size_t)r * L_; cols = L_;
        }
        float* ps  = (float*)smem;       // 4
        float* ps2 = ps + 4;             // 4
        float* st  = ps + 8;             // mu, rstd
        bool act = tid * 4 < cols;
        float4 v = act ? *(const float4*)&rp[tid * 4] : make_float4(0.f, 0.f, 0.f, 0.f);
        float s = v.x + v.y + v.z + v.w;
        float s2 = v.x * v.x + v.y * v.y + v.z * v.z + v.w * v.w;
        for (int off = 32; off; off >>= 1) {
            s  += __shfl_down(s,  off, 64);
            s2 += __shfl_down(s2, off, 64);
        }
        int wid = tid >> 6, lid = tid & 63;
        if (lid == 0) { ps[wid] = s; ps2[wid] = s2; }
        __syncthreads();
        if (tid == 0) {
            float t = ps[0] + ps[1] + ps[2] + ps[3];
            float t2 = ps2[0] + ps2[1] + ps2[2] + ps2[3];
            float m = t / cols;
            float var = t2 / cols - m * m;
            st[0] = m; st[1] = rsqrtf(var + 1e-5f);
        }
        __syncthreads();
        if (!act) return;
        float mu = st[0], rstd = st[1];
        float4 gv = *(const float4*)&g[tid * 4];
        float4 bv = *(const float4*)&bb[tid * 4];
        float o0 = (v.x - mu) * rstd * gv.x + bv.x;
        float o1 = (v.y - mu) * rstd * gv.y + bv.y;
        float o2 = (v.z - mu) * rstd * gv.z + bv.z;
        float o3 = (v.w - mu) * rstd * gv.w + bv.w;
        ushort4 uo;
        bf16 h0 = __float2bfloat16(o0); uo.x = *(ushort*)&h0;
        bf16 h1 = __float2bfloat16(o1); uo.y = *(ushort*)&h1;
        bf16 h2 = __float2bfloat16(o2); uo.z = *(ushort*)&h2;
        bf16 h3 = __float2bfloat16(o3); uo.w = *(ushort*)&h3;
        *(ushort4*)&op[tid * 4] = uo;
    } else if (bid < 11136) {
        // ---------------- weight transpose+convert ------------------------
        ushort (*t)[65] = (ushort(*)[65])smem;
        int id = bid - 10240;
        int xb = id & 15, y = id >> 4;
        const float* W; bf16* Wt; int K, ky;
        if (y < 16)      { W = Wq; Wt = wqt; K = 1024; ky = y; }
        else if (y < 28) { W = Wk; Wt = wkt; K = 768;  ky = y - 16; }
        else if (y < 40) { W = Wv; Wt = wvt; K = 768;  ky = y - 28; }
        else             { W = Wo; Wt = wot; K = 1024; ky = y - 40; }
        int k0 = ky * 64, n0 = xb * 64;
#pragma unroll
        for (int i = 0; i < 16; i++) {
            int e = tid + i * 256;
            int r = e >> 6, c = e & 63;
            bf16 hv = __float2bfloat16(W[(size_t)(k0 + r) * D_ + n0 + c]);
            t[r][c] = *(ushort*)&hv;
        }
        __syncthreads();
#pragma unroll
        for (int i = 0; i < 16; i++) {
            int e = tid + i * 256;
            int r = e >> 6, c = e & 63;
            ushort uv = t[c][r];
            Wt[(size_t)(n0 + r) * K + k0 + c] = *(bf16*)&uv;
        }
    } else {
        // ---------------- emb1: silu(emb) @ Wemb partial dots -------------
        float* se  = (float*)smem;          // 2048 f32 = 8 KB
        float* red = (float*)(smem + 8192); // [4][8][64] f32 = 8 KB
        int id = bid - 11136;
        int j0 = (id & 31) * 64;
        int ks = id >> 5;
        int tx = tid & 15, ty = tid >> 4;
        int w = tid >> 6, lane = tid & 63;
#pragma unroll
        for (int b = 0; b < 8; b++) {
            float xv = emb[b * TE_ + ks * 256 + tid];
            se[b * 256 + tid] = xv / (1.f + __expf(-xv));
        }
        __syncthreads();
        float acc[8][4] = {};
#pragma unroll 4
        for (int i = 0; i < 16; i++) {
            int e = ty + 16 * i;
            float4 wv = *(const float4*)&Wemb[(size_t)(ks * 256 + e) * 2048 + j0 + tx * 4];
#pragma unroll
            for (int b = 0; b < 8; b++) {
                float s = se[b * 256 + e];
                acc[b][0] += s * wv.x; acc[b][1] += s * wv.y;
                acc[b][2] += s * wv.z; acc[b][3] += s * wv.w;
            }
        }
#pragma unroll
        for (int b = 0; b < 8; b++)
#pragma unroll
            for (int m = 0; m < 4; m++) {
                float v = acc[b][m];
                v += __shfl_down(v, 32, 64);
                v += __shfl_down(v, 16, 64);
                if (lane < 16) red[(w * 8 + b) * 64 + lane * 4 + m] = v;
            }
        __syncthreads();
        for (int o = tid; o < 512; o += 256) {
            int b = o >> 6, jl = o & 63;
            float s = red[(0 * 8 + b) * 64 + jl] + red[(1 * 8 + b) * 64 + jl]
                    + red[(2 * 8 + b) * 64 + jl] + red[(3 * 8 + b) * 64 + jl];
            part[((size_t)ks * 8 + b) * 2048 + j0 + jl] = s;
        }
    }
}

// ===== MFMA GEMM body: 128x64 tile, BK=64, DMA staging, 6 blocks/CU =======
// MODE 0: bf16 C  MODE 1: f32 C + res  MODE 2: V-scatter pre-swizzled vT
template <int MODE>
__device__ __forceinline__ void gemm_body(const ushort* __restrict__ Ap,
                                          const ushort* __restrict__ Bp,
                                          const float* __restrict__ bias,
                                          const float* __restrict__ res,
                                          void* __restrict__ Cout,
                                          int m0, int n0, int Ncols, int K,
                                          ushort* Ash, ushort* Bsh) {
    int tid = threadIdx.x;
    int w = tid >> 6, lane = tid & 63;
    int quad = lane >> 4, l15 = lane & 15;
    int wm = (w >> 1) * 64, wn = (w & 1) * 32;
    int lr8 = lane >> 3;
    int sc  = lane & 7;
    int gc  = sc ^ lr8;
    f32x4 acc[4][2] = {};
    for (int kt = 0; kt < K; kt += 64) {
#pragma unroll
        for (int j = 0; j < 4; j++) {
            int rbase = w * 32 + j * 8;
            gld16(&Ap[(size_t)(m0 + rbase + lr8) * K + kt + gc * 8], &Ash[rbase * 64]);
        }
#pragma unroll
        for (int j = 0; j < 2; j++) {
            int rbase = w * 16 + j * 8;
            gld16(&Bp[(size_t)(n0 + rbase + lr8) * K + kt + gc * 8], &Bsh[rbase * 64]);
        }
        __syncthreads();
#pragma unroll
        for (int kh = 0; kh < 2; kh++) {
            bf16x8 af[4], bfr[2];
#pragma unroll
            for (int mt = 0; mt < 4; mt++)
                af[mt] = *(bf16x8*)&Ash[(wm + mt * 16 + l15) * 64 + (((kh * 4 + quad) ^ (l15 & 7)) * 8)];
#pragma unroll
            for (int nt = 0; nt < 2; nt++)
                bfr[nt] = *(bf16x8*)&Bsh[(wn + nt * 16 + l15) * 64 + (((kh * 4 + quad) ^ (l15 & 7)) * 8)];
#pragma unroll
            for (int mt = 0; mt < 4; mt++)
#pragma unroll
                for (int nt = 0; nt < 2; nt++)
                    acc[mt][nt] = __builtin_amdgcn_mfma_f32_16x16x32_bf16(af[mt], bfr[nt], acc[mt][nt], 0, 0, 0);
        }
        __syncthreads();
    }
#pragma unroll
    for (int mt = 0; mt < 4; mt++) {
#pragma unroll
        for (int nt = 0; nt < 2; nt++) {
#pragma unroll
            for (int reg = 0; reg < 4; reg++) {
                int row = m0 + wm + mt * 16 + quad * 4 + reg;
                int col = n0 + wn + nt * 16 + l15;
                float v = acc[mt][nt][reg] + bias[col];
                if (MODE == 1) {
                    v += res[(size_t)row * Ncols + col];
                    ((float*)Cout)[(size_t)row * Ncols + col] = v;
                } else if (MODE == 0) {
                    ((bf16*)Cout)[(size_t)row * Ncols + col] = __float2bfloat16(v);
                } else {
                    int b = row >> 8, n = row & 255;
                    int h = col >> 6, d = col & 63;
                    size_t addr = ((size_t)(b * 16 + h) * 64 + d) * 256
                                + (((n >> 3) ^ (d & 7)) * 8) + (n & 7);
                    ((bf16*)Cout)[addr] = __float2bfloat16(v);
                }
            }
        }
    }
}

// ===== fused Q/K/V projection + emb2 tail. XCD-local m mapping ============
// Q [0,1024) | K [1024,1280) | V [1280,1536) | emb2 [1536,1600)
__global__ __launch_bounds__(256) void qkv_gemm(const bf16* __restrict__ xn,
                                                const bf16* __restrict__ xfn,
                                                const bf16* __restrict__ wqt,
                                                const bf16* __restrict__ wkt,
                                                const bf16* __restrict__ wvt,
                                                const float* __restrict__ bq,
                                                const float* __restrict__ bk,
                                                const float* __restrict__ bv,
                                                bf16* __restrict__ q,
                                                bf16* __restrict__ kbuf,
                                                bf16* __restrict__ vT,
                                                const float* __restrict__ part,
                                                const float* __restrict__ bemb,
                                                float* __restrict__ embo) {
    __shared__ ushort Ash[128 * 64];
    __shared__ ushort Bsh[64 * 64];
    int bid = blockIdx.x;
    if (bid < 1024) {
        gemm_body<0>((const ushort*)xn, (const ushort*)wqt, bq, nullptr, q,
                     (bid & 63) * 128, (bid >> 6) * 64, D_, D_, Ash, Bsh);
    } else if (bid < 1280) {
        int id = bid - 1024;
        gemm_body<0>((const ushort*)xfn, (const ushort*)wkt, bk, nullptr, kbuf,
                     (id & 15) * 128, (id >> 4) * 64, D_, L_, Ash, Bsh);
    } else if (bid < 1536) {
        int id = bid - 1280;
        gemm_body<2>((const ushort*)xfn, (const ushort*)wvt, bv, nullptr, vT,
                     (id & 15) * 128, (id >> 4) * 64, D_, L_, Ash, Bsh);
    } else {
        int o = (bid - 1536) * 256 + threadIdx.x;
        int b = o >> 11, j = o & 2047;
        float s = bemb[j];
#pragma unroll
        for (int ks = 0; ks < 8; ks++) s += part[((size_t)ks * 8 + b) * 2048 + j];
        embo[o] = s;
    }
}

// ===== output projection + residual (f32 out) =============================
__global__ __launch_bounds__(256) void out_gemm(const bf16* __restrict__ a,
                                                const bf16* __restrict__ wot,
                                                const float* __restrict__ bout,
                                                const float* __restrict__ x,
                                                float* __restrict__ out) {
    __shared__ ushort Ash[128 * 64];
    __shared__ ushort Bsh[64 * 64];
    int bid = blockIdx.x;
    gemm_body<1>((const ushort*)a, (const ushort*)wot, bout, x, out,
                 (bid & 63) * 128, (bid >> 6) * 64, D_, D_, Ash, Bsh);
}

// ===== MFMA attention: block = 64 q-rows x one (b,h) ======================
__global__ __launch_bounds__(256) void attn_mfma(const bf16* __restrict__ q,
                                                 const bf16* __restrict__ k,
                                                 const bf16* __restrict__ vT,
                                                 bf16* __restrict__ y) {
    __shared__ ushort KV[N_ * HD_];
    __shared__ ushort P[64 * N_];
    int tid = threadIdx.x;
    int w = tid >> 6, lane = tid & 63;
    int quad = lane >> 4, l15 = lane & 15;
    int t0 = blockIdx.x * 64;
    int bh = blockIdx.y;
    int b = bh >> 4, h = bh & 15;

    const ushort* kp = (const ushort*)k;
    const ushort* qp = (const ushort*)q;
    const ushort* vp = (const ushort*)vT;
    int lr8 = lane >> 3, sc = lane & 7, gc = sc ^ lr8;

#pragma unroll
    for (int j = 0; j < 8; j++) {
        int rbase = w * 64 + j * 8;
        gld16(&kp[(size_t)(b * N_ + rbase + lr8) * D_ + h * 64 + gc * 8], &KV[rbase * 64]);
    }
#pragma unroll
    for (int j = 0; j < 2; j++) {
        int rbase = w * 16 + j * 8;
        gld16(&qp[(size_t)(b * T_ + t0 + rbase + lr8) * D_ + h * 64 + gc * 8], &P[rbase * 64]);
    }
    __syncthreads();

    int qrow = w * 16 + l15;
    bf16x8 aq[2];
#pragma unroll
    for (int kk = 0; kk < 2; kk++)
        aq[kk] = *(bf16x8*)&P[qrow * 64 + (((kk * 4 + quad) ^ (qrow & 7)) * 8)];
    f32x4 sf[16];
#pragma unroll
    for (int nt = 0; nt < 16; nt++) {
        int n = nt * 16 + l15;
        bf16x8 b0 = *(bf16x8*)&KV[n * 64 + (((0 + quad) ^ (n & 7)) * 8)];
        bf16x8 b1 = *(bf16x8*)&KV[n * 64 + (((4 + quad) ^ (n & 7)) * 8)];
        f32x4 z = {};
        f32x4 t = __builtin_amdgcn_mfma_f32_16x16x32_bf16(aq[0], b0, z, 0, 0, 0);
        sf[nt] = __builtin_amdgcn_mfma_f32_16x16x32_bf16(aq[1], b1, t, 0, 0, 0);
    }
    __syncthreads();

    const ushort* vbase = vp + (size_t)(b * 16 + h) * 16384;
#pragma unroll
    for (int j = 0; j < 8; j++) {
        gld16(&vbase[(w * 8 + j) * 512 + lane * 8], &KV[(w * 8 + j) * 512]);
    }

    const float scale = 0.125f;
    float mx[4] = {-1e30f, -1e30f, -1e30f, -1e30f};
#pragma unroll
    for (int nt = 0; nt < 16; nt++)
#pragma unroll
        for (int reg = 0; reg < 4; reg++) mx[reg] = fmaxf(mx[reg], sf[nt][reg]);
#pragma unroll
    for (int off = 1; off < 16; off <<= 1)
#pragma unroll
        for (int reg = 0; reg < 4; reg++)
            mx[reg] = fmaxf(mx[reg], __shfl_xor(mx[reg], off, 64));
    float sm[4] = {0.f, 0.f, 0.f, 0.f};
#pragma unroll
    for (int nt = 0; nt < 16; nt++)
#pragma unroll
        for (int reg = 0; reg < 4; reg++) {
            float e = __expf((sf[nt][reg] - mx[reg]) * scale);
            sf[nt][reg] = e;
            sm[reg] += e;
        }
#pragma unroll
    for (int off = 1; off < 16; off <<= 1)
#pragma unroll
        for (int reg = 0; reg < 4; reg++)
            sm[reg] += __shfl_xor(sm[reg], off, 64);
    float inv[4];
#pragma unroll
    for (int reg = 0; reg < 4; reg++) inv[reg] = 1.f / sm[reg];

#pragma unroll
    for (int nt = 0; nt < 16; nt++)
#pragma unroll
        for (int reg = 0; reg < 4; reg++) {
            int r = w * 16 + quad * 4 + reg;
            int colc = nt * 2 + (l15 >> 3);
            int addr = r * 256 + ((colc ^ (r & 7)) * 8) + (l15 & 7);
            bf16 hv = __float2bfloat16(sf[nt][reg]);
            P[addr] = *(ushort*)&hv;
        }
    __syncthreads();

    f32x4 of[4] = {};
    int prow = w * 16 + l15;
#pragma unroll
    for (int kk = 0; kk < 8; kk++) {
        bf16x8 ap = *(bf16x8*)&P[prow * 256 + (((kk * 4 + quad) ^ (prow & 7)) * 8)];
#pragma unroll
        for (int dt = 0; dt < 4; dt++) {
            int d = dt * 16 + l15;
            bf16x8 bv = *(bf16x8*)&KV[d * 256 + (((kk * 4 + quad) ^ (d & 7)) * 8)];
            of[dt] = __builtin_amdgcn_mfma_f32_16x16x32_bf16(ap, bv, of[dt], 0, 0, 0);
        }
    }
#pragma unroll
    for (int dt = 0; dt < 4; dt++)
#pragma unroll
        for (int reg = 0; reg < 4; reg++) {
            int r = t0 + w * 16 + quad * 4 + reg;
            y[((size_t)(b * T_ + r) * D_) + h * 64 + dt * 16 + l15] =
                __float2bfloat16(of[dt][reg] * inv[reg]);
        }
}

// ===== stylization, vectorized 4 cols/thread ==============================
__global__ __launch_bounds__(256) void styl_kernel(const bf16* __restrict__ y,
                                                   const float* __restrict__ g,
                                                   const float* __restrict__ bb,
                                                   const float* __restrict__ embo,
                                                   bf16* __restrict__ a) {
    int row = blockIdx.x;
    int b = row >> 10;
    int tid = threadIdx.x;
    const ushort* rp = (const ushort*)(y + (size_t)row * D_);
    ushort4 uy = *(const ushort4*)&rp[tid * 4];
    float v0 = bitf((unsigned)uy.x << 16), v1 = bitf((unsigned)uy.y << 16);
    float v2 = bitf((unsigned)uy.z << 16), v3 = bitf((unsigned)uy.w << 16);
    float s = v0 + v1 + v2 + v3;
    float s2 = v0 * v0 + v1 * v1 + v2 * v2 + v3 * v3;
    for (int off = 32; off; off >>= 1) {
        s  += __shfl_down(s,  off, 64);
        s2 += __shfl_down(s2, off, 64);
    }
    __shared__ float ps[4], ps2[4];
    __shared__ float smu, srstd;
    int wid = tid >> 6, lid = tid & 63;
    if (lid == 0) { ps[wid] = s; ps2[wid] = s2; }
    __syncthreads();
    if (tid == 0) {
        float t = ps[0] + ps[1] + ps[2] + ps[3];
        float t2 = ps2[0] + ps2[1] + ps2[2] + ps2[3];
        float m = t / D_;
        float var = t2 / D_ - m * m;
        smu = m; srstd = rsqrtf(var + 1e-5f);
    }
    __syncthreads();
    float mu = smu, rstd = srstd;
    float4 gv = *(const float4*)&g[tid * 4];
    float4 bv = *(const float4*)&bb[tid * 4];
    float4 scv = *(const float4*)&embo[b * 2048 + tid * 4];
    float4 shv = *(const float4*)&embo[b * 2048 + 1024 + tid * 4];
    float n0 = (v0 - mu) * rstd * gv.x + bv.x;
    float n1 = (v1 - mu) * rstd * gv.y + bv.y;
    float n2 = (v2 - mu) * rstd * gv.z + bv.z;
    float n3 = (v3 - mu) * rstd * gv.w + bv.w;
    float h0 = n0 * (1.f + scv.x) + shv.x;
    float h1 = n1 * (1.f + scv.y) + shv.y;
    float h2 = n2 * (1.f + scv.z) + shv.z;
    float h3 = n3 * (1.f + scv.w) + shv.w;
    h0 = h0 / (1.f + __expf(-h0));
    h1 = h1 / (1.f + __expf(-h1));
    h2 = h2 / (1.f + __expf(-h2));
    h3 = h3 / (1.f + __expf(-h3));
    ushort4 uo;
    bf16 t0 = __float2bfloat16(h0); uo.x = *(ushort*)&t0;
    bf16 t1 = __float2bfloat16(h1); uo.y = *(ushort*)&t1;
    bf16 t2 = __float2bfloat16(h2); uo.z = *(ushort*)&t2;
    bf16 t3 = __float2bfloat16(h3); uo.w = *(ushort*)&t3;
    *(ushort4*)&((ushort*)a)[(size_t)row * D_ + tid * 4] = uo;
}

extern "C" void kernel_launch(void* const* d_in, const int* in_sizes, int n_in,
                              void* d_out, int out_size, void* d_ws, size_t ws_size,
                              hipStream_t stream) {
    const float* x    = (const float*)d_in[0];
    const float* xf   = (const float*)d_in[1];
    const float* emb  = (const float*)d_in[2];
    const float* ln_g = (const float*)d_in[3];
    const float* ln_b = (const float*)d_in[4];
    const float* cln_g= (const float*)d_in[5];
    const float* cln_b= (const float*)d_in[6];
    const float* Wq   = (const float*)d_in[7];
    const float* bq   = (const float*)d_in[8];
    const float* Wk   = (const float*)d_in[9];
    const float* bk   = (const float*)d_in[10];
    const float* Wv   = (const float*)d_in[11];
    const float* bv   = (const float*)d_in[12];
    const float* sln_g= (const float*)d_in[13];
    const float* sln_b= (const float*)d_in[14];
    const float* Wemb = (const float*)d_in[15];
    const float* bemb = (const float*)d_in[16];
    const float* Wout = (const float*)d_in[17];
    const float* bout = (const float*)d_in[18];
    float* out = (float*)d_out;

    char* wsp = (char*)d_ws;
    bf16*  xn   = (bf16*)(wsp);                   // 8192x1024 bf16 16MB (reused as y)
    bf16*  xfn  = (bf16*)(wsp + 16777216);        // 2048x768  bf16  3MB
    bf16*  q    = (bf16*)(wsp + 19922944);        // 8192x1024 bf16 16MB (reused as a)
    bf16*  kbuf = (bf16*)(wsp + 36700160);        // 2048x1024 bf16  4MB
    bf16*  vT   = (bf16*)(wsp + 40894464);        // [b][h][64][256] bf16 4MB pre-swizzled
    float* embo = (float*)(wsp + 45088768);       // 8x2048    f32  64KB
    bf16*  wqt  = (bf16*)(wsp + 45154304);        // 1024x1024 bf16  2MB
    bf16*  wkt  = (bf16*)(wsp + 47251456);        // 1024x768  bf16 1.5MB
    bf16*  wvt  = (bf16*)(wsp + 48824320);        // 1024x768  bf16 1.5MB
    bf16*  wot  = (bf16*)(wsp + 50397184);        // 1024x1024 bf16  2MB
    float* part = (float*)(wsp + 52494336);       // 8x8x2048  f32  512KB
    bf16*  ybuf = xn;
    bf16*  abuf = q;

    prep_kernel<<<11392, 256, 0, stream>>>(x, xf, ln_g, ln_b, cln_g, cln_b,
                                           Wq, Wk, Wv, Wout, emb, Wemb,
                                           xn, xfn, wqt, wkt, wvt, wot, part);

    qkv_gemm<<<1600, 256, 0, stream>>>(xn, xfn, wqt, wkt, wvt, bq, bk, bv,
                                       q, kbuf, vT, part, bemb, embo);

    attn_mfma<<<dim3(16, 128), 256, 0, stream>>>(q, kbuf, vT, ybuf);

    styl_kernel<<<B_ * T_, 256, 0, stream>>>(ybuf, sln_g, sln_b, embo, abuf);

    out_gemm<<<1024, 256, 0, stream>>>(abuf, wot, bout, x, out);
}

// Round 8
// 242.026 us; speedup vs baseline: 5.3275x; 1.0567x over previous
//
#include <hip/hip_runtime.h>
#include <hip/hip_bf16.h>

typedef __hip_bfloat16 bf16;
typedef unsigned short ushort;
typedef unsigned char uchar;
typedef long i64;   // 64-bit on amdgcn
typedef __attribute__((ext_vector_type(8))) short bf16x8;
typedef __attribute__((ext_vector_type(4))) float f32x4;

#define B_ 8
#define T_ 1024
#define D_ 1024
#define N_ 256
#define L_ 768
#define H_ 16
#define HD_ 64
#define TE_ 2048

__device__ __forceinline__ void gld16(const void* g, void* l) {
    __builtin_amdgcn_global_load_lds((const __attribute__((address_space(1))) void*)g,
                                     (__attribute__((address_space(3))) void*)l,
                                     16, 0, 0);
}

__device__ __forceinline__ float bitf(unsigned u) { return __uint_as_float(u); }

// pack 4 f32 -> 4 fp8 e4m3 bytes (OCP on gfx950)
__device__ __forceinline__ int pk4_fp8(float a, float b, float c, float d) {
    int p = __builtin_amdgcn_cvt_pk_fp8_f32(a, b, 0, false);
    p = __builtin_amdgcn_cvt_pk_fp8_f32(c, d, p, true);
    return p;
}
__device__ __forceinline__ uchar pk1_fp8(float a) {
    int p = __builtin_amdgcn_cvt_pk_fp8_f32(a, a, 0, false);
    return (uchar)(p & 0xff);
}

// ===== prep: LN(x)+LN(xf)->fp8 [0,10240) | tcvt4->fp8 [10240,11136) | emb1 [11136,11392)
__global__ __launch_bounds__(256) void prep_kernel(
        const float* __restrict__ x, const float* __restrict__ xf,
        const float* __restrict__ g1, const float* __restrict__ b1,
        const float* __restrict__ g2, const float* __restrict__ b2,
        const float* __restrict__ Wq, const float* __restrict__ Wk,
        const float* __restrict__ Wv, const float* __restrict__ Wo,
        const float* __restrict__ emb, const float* __restrict__ Wemb,
        uchar* __restrict__ xn8, uchar* __restrict__ xfn8,
        uchar* __restrict__ wq8, uchar* __restrict__ wk8,
        uchar* __restrict__ wv8, uchar* __restrict__ wo8,
        float* __restrict__ part) {
    __shared__ __align__(16) char smem[16384];
    int bid = blockIdx.x;
    int tid = threadIdx.x;
    if (bid < 10240) {
        // LayerNorm, 4 cols/thread, fp8 out
        const float *rp, *g, *bb; uchar* op; int cols;
        if (bid < B_ * T_) {
            rp = x + (size_t)bid * D_; g = g1; bb = b1; op = xn8 + (size_t)bid * D_; cols = D_;
        } else {
            int r = bid - B_ * T_;
            rp = xf + (size_t)r * L_; g = g2; bb = b2; op = xfn8 + (size_t)r * L_; cols = L_;
        }
        float* ps  = (float*)smem;
        float* ps2 = ps + 4;
        float* st  = ps + 8;
        bool act = tid * 4 < cols;
        float4 v = act ? *(const float4*)&rp[tid * 4] : make_float4(0.f, 0.f, 0.f, 0.f);
        float s = v.x + v.y + v.z + v.w;
        float s2 = v.x * v.x + v.y * v.y + v.z * v.z + v.w * v.w;
        for (int off = 32; off; off >>= 1) {
            s  += __shfl_down(s,  off, 64);
            s2 += __shfl_down(s2, off, 64);
        }
        int wid = tid >> 6, lid = tid & 63;
        if (lid == 0) { ps[wid] = s; ps2[wid] = s2; }
        __syncthreads();
        if (tid == 0) {
            float t = ps[0] + ps[1] + ps[2] + ps[3];
            float t2 = ps2[0] + ps2[1] + ps2[2] + ps2[3];
            float m = t / cols;
            float var = t2 / cols - m * m;
            st[0] = m; st[1] = rsqrtf(var + 1e-5f);
        }
        __syncthreads();
        if (!act) return;
        float mu = st[0], rstd = st[1];
        float4 gv = *(const float4*)&g[tid * 4];
        float4 bv = *(const float4*)&bb[tid * 4];
        float o0 = (v.x - mu) * rstd * gv.x + bv.x;
        float o1 = (v.y - mu) * rstd * gv.y + bv.y;
        float o2 = (v.z - mu) * rstd * gv.z + bv.z;
        float o3 = (v.w - mu) * rstd * gv.w + bv.w;
        *(int*)&op[tid * 4] = pk4_fp8(o0, o1, o2, o3);
    } else if (bid < 11136) {
        // weight transpose + f32->fp8: W(KxNc) -> Wt(NcxK)
        uchar (*t)[65] = (uchar(*)[65])smem;
        int id = bid - 10240;
        int xb = id & 15, y = id >> 4;
        const float* W; uchar* Wt; int K, ky;
        if (y < 16)      { W = Wq; Wt = wq8; K = 1024; ky = y; }
        else if (y < 28) { W = Wk; Wt = wk8; K = 768;  ky = y - 16; }
        else if (y < 40) { W = Wv; Wt = wv8; K = 768;  ky = y - 28; }
        else             { W = Wo; Wt = wo8; K = 1024; ky = y - 40; }
        int k0 = ky * 64, n0 = xb * 64;
#pragma unroll
        for (int i = 0; i < 16; i++) {
            int e = tid + i * 256;
            int r = e >> 6, c = e & 63;
            t[r][c] = pk1_fp8(W[(size_t)(k0 + r) * D_ + n0 + c]);
        }
        __syncthreads();
#pragma unroll
        for (int i = 0; i < 4; i++) {
            int e = tid + i * 256;          // 1024 writes of 4B
            int r = e >> 4, cg = (e & 15) * 4;
            unsigned u = (unsigned)t[cg][r] | ((unsigned)t[cg + 1][r] << 8)
                       | ((unsigned)t[cg + 2][r] << 16) | ((unsigned)t[cg + 3][r] << 24);
            *(unsigned*)&Wt[(size_t)(n0 + r) * K + k0 + cg] = u;
        }
    } else {
        // emb1: silu(emb) @ Wemb partial dots
        float* se  = (float*)smem;
        float* red = (float*)(smem + 8192);
        int id = bid - 11136;
        int j0 = (id & 31) * 64;
        int ks = id >> 5;
        int tx = tid & 15, ty = tid >> 4;
        int w = tid >> 6, lane = tid & 63;
#pragma unroll
        for (int b = 0; b < 8; b++) {
            float xv = emb[b * TE_ + ks * 256 + tid];
            se[b * 256 + tid] = xv / (1.f + __expf(-xv));
        }
        __syncthreads();
        float acc[8][4] = {};
#pragma unroll 4
        for (int i = 0; i < 16; i++) {
            int e = ty + 16 * i;
            float4 wv = *(const float4*)&Wemb[(size_t)(ks * 256 + e) * 2048 + j0 + tx * 4];
#pragma unroll
            for (int b = 0; b < 8; b++) {
                float s = se[b * 256 + e];
                acc[b][0] += s * wv.x; acc[b][1] += s * wv.y;
                acc[b][2] += s * wv.z; acc[b][3] += s * wv.w;
            }
        }
#pragma unroll
        for (int b = 0; b < 8; b++)
#pragma unroll
            for (int m = 0; m < 4; m++) {
                float v = acc[b][m];
                v += __shfl_down(v, 32, 64);
                v += __shfl_down(v, 16, 64);
                if (lane < 16) red[(w * 8 + b) * 64 + lane * 4 + m] = v;
            }
        __syncthreads();
        for (int o = tid; o < 512; o += 256) {
            int b = o >> 6, jl = o & 63;
            float s = red[(0 * 8 + b) * 64 + jl] + red[(1 * 8 + b) * 64 + jl]
                    + red[(2 * 8 + b) * 64 + jl] + red[(3 * 8 + b) * 64 + jl];
            part[((size_t)ks * 8 + b) * 2048 + j0 + jl] = s;
        }
    }
}

// ===== fp8 MFMA GEMM body: 128x64 tile, BK=128, DMA staging ===============
// MODE 0: bf16 C  MODE 1: f32 C + res  MODE 2: V-scatter pre-swizzled vT
// LDS rows 128 B = 8x16B chunks, chunk swizzle c4^(r&7); frag reads 8B, 2-way max.
template <int MODE>
__device__ __forceinline__ void gemm_body(const uchar* __restrict__ Ap,
                                          const uchar* __restrict__ Bp,
                                          const float* __restrict__ bias,
                                          const float* __restrict__ res,
                                          void* __restrict__ Cout,
                                          int m0, int n0, int Ncols, int K,
                                          uchar* Ash, uchar* Bsh) {
    int tid = threadIdx.x;
    int w = tid >> 6, lane = tid & 63;
    int quad = lane >> 4, l15 = lane & 15;
    int wm = (w >> 1) * 64, wn = (w & 1) * 32;
    int lr8 = lane >> 3;
    int sc  = lane & 7;
    int gc  = sc ^ lr8;          // 16B chunk this lane fetches
    f32x4 acc[4][2] = {};
    for (int kt = 0; kt < K; kt += 128) {
#pragma unroll
        for (int j = 0; j < 4; j++) {
            int rbase = w * 32 + j * 8;
            gld16(&Ap[(size_t)(m0 + rbase + lr8) * K + kt + gc * 16], &Ash[rbase * 128]);
        }
#pragma unroll
        for (int j = 0; j < 2; j++) {
            int rbase = w * 16 + j * 8;
            gld16(&Bp[(size_t)(n0 + rbase + lr8) * K + kt + gc * 16], &Bsh[rbase * 128]);
        }
        __syncthreads();
#pragma unroll
        for (int kh = 0; kh < 4; kh++) {
            int c4 = kh * 2 + (quad >> 1);
            int sub = (quad & 1) * 8;
            int pos = (c4 ^ (l15 & 7)) * 16 + sub;
            i64 af[4], bfr[2];
#pragma unroll
            for (int mt = 0; mt < 4; mt++)
                af[mt] = *(const i64*)&Ash[(wm + mt * 16 + l15) * 128 + pos];
#pragma unroll
            for (int nt = 0; nt < 2; nt++)
                bfr[nt] = *(const i64*)&Bsh[(wn + nt * 16 + l15) * 128 + pos];
#pragma unroll
            for (int mt = 0; mt < 4; mt++)
#pragma unroll
                for (int nt = 0; nt < 2; nt++)
                    acc[mt][nt] = __builtin_amdgcn_mfma_f32_16x16x32_fp8_fp8(af[mt], bfr[nt], acc[mt][nt], 0, 0, 0);
        }
        __syncthreads();
    }
#pragma unroll
    for (int mt = 0; mt < 4; mt++) {
#pragma unroll
        for (int nt = 0; nt < 2; nt++) {
#pragma unroll
            for (int reg = 0; reg < 4; reg++) {
                int row = m0 + wm + mt * 16 + quad * 4 + reg;
                int col = n0 + wn + nt * 16 + l15;
                float v = acc[mt][nt][reg] + bias[col];
                if (MODE == 1) {
                    v += res[(size_t)row * Ncols + col];
                    ((float*)Cout)[(size_t)row * Ncols + col] = v;
                } else if (MODE == 0) {
                    ((bf16*)Cout)[(size_t)row * Ncols + col] = __float2bfloat16(v);
                } else {
                    int b = row >> 8, n = row & 255;
                    int h = col >> 6, d = col & 63;
                    size_t addr = ((size_t)(b * 16 + h) * 64 + d) * 256
                                + (((n >> 3) ^ (d & 7)) * 8) + (n & 7);
                    ((bf16*)Cout)[addr] = __float2bfloat16(v);
                }
            }
        }
    }
}

// ===== fused Q/K/V projection + emb2 tail. XCD-local m mapping ============
__global__ __launch_bounds__(256) void qkv_gemm(const uchar* __restrict__ xn8,
                                                const uchar* __restrict__ xfn8,
                                                const uchar* __restrict__ wq8,
                                                const uchar* __restrict__ wk8,
                                                const uchar* __restrict__ wv8,
                                                const float* __restrict__ bq,
                                                const float* __restrict__ bk,
                                                const float* __restrict__ bv,
                                                bf16* __restrict__ q,
                                                bf16* __restrict__ kbuf,
                                                bf16* __restrict__ vT,
                                                const float* __restrict__ part,
                                                const float* __restrict__ bemb,
                                                float* __restrict__ embo) {
    __shared__ __align__(16) uchar Ash[128 * 128];
    __shared__ __align__(16) uchar Bsh[64 * 128];
    int bid = blockIdx.x;
    if (bid < 1024) {
        gemm_body<0>(xn8, wq8, bq, nullptr, q,
                     (bid & 63) * 128, (bid >> 6) * 64, D_, D_, Ash, Bsh);
    } else if (bid < 1280) {
        int id = bid - 1024;
        gemm_body<0>(xfn8, wk8, bk, nullptr, kbuf,
                     (id & 15) * 128, (id >> 4) * 64, D_, L_, Ash, Bsh);
    } else if (bid < 1536) {
        int id = bid - 1280;
        gemm_body<2>(xfn8, wv8, bv, nullptr, vT,
                     (id & 15) * 128, (id >> 4) * 64, D_, L_, Ash, Bsh);
    } else {
        int o = (bid - 1536) * 256 + threadIdx.x;
        int b = o >> 11, j = o & 2047;
        float s = bemb[j];
#pragma unroll
        for (int ks = 0; ks < 8; ks++) s += part[((size_t)ks * 8 + b) * 2048 + j];
        embo[o] = s;
    }
}

// ===== output projection + residual (f32 out) =============================
__global__ __launch_bounds__(256) void out_gemm(const uchar* __restrict__ a8,
                                                const uchar* __restrict__ wo8,
                                                const float* __restrict__ bout,
                                                const float* __restrict__ x,
                                                float* __restrict__ out) {
    __shared__ __align__(16) uchar Ash[128 * 128];
    __shared__ __align__(16) uchar Bsh[64 * 128];
    int bid = blockIdx.x;
    gemm_body<1>(a8, wo8, bout, x, out,
                 (bid & 63) * 128, (bid >> 6) * 64, D_, D_, Ash, Bsh);
}

// ===== MFMA attention: block = 64 q-rows x one (b,h) (bf16, unchanged) ====
__global__ __launch_bounds__(256) void attn_mfma(const bf16* __restrict__ q,
                                                 const bf16* __restrict__ k,
                                                 const bf16* __restrict__ vT,
                                                 bf16* __restrict__ y) {
    __shared__ ushort KV[N_ * HD_];
    __shared__ ushort P[64 * N_];
    int tid = threadIdx.x;
    int w = tid >> 6, lane = tid & 63;
    int quad = lane >> 4, l15 = lane & 15;
    int t0 = blockIdx.x * 64;
    int bh = blockIdx.y;
    int b = bh >> 4, h = bh & 15;

    const ushort* kp = (const ushort*)k;
    const ushort* qp = (const ushort*)q;
    const ushort* vp = (const ushort*)vT;
    int lr8 = lane >> 3, sc = lane & 7, gc = sc ^ lr8;

#pragma unroll
    for (int j = 0; j < 8; j++) {
        int rbase = w * 64 + j * 8;
        gld16(&kp[(size_t)(b * N_ + rbase + lr8) * D_ + h * 64 + gc * 8], &KV[rbase * 64]);
    }
#pragma unroll
    for (int j = 0; j < 2; j++) {
        int rbase = w * 16 + j * 8;
        gld16(&qp[(size_t)(b * T_ + t0 + rbase + lr8) * D_ + h * 64 + gc * 8], &P[rbase * 64]);
    }
    __syncthreads();

    int qrow = w * 16 + l15;
    bf16x8 aq[2];
#pragma unroll
    for (int kk = 0; kk < 2; kk++)
        aq[kk] = *(bf16x8*)&P[qrow * 64 + (((kk * 4 + quad) ^ (qrow & 7)) * 8)];
    f32x4 sf[16];
#pragma unroll
    for (int nt = 0; nt < 16; nt++) {
        int n = nt * 16 + l15;
        bf16x8 b0 = *(bf16x8*)&KV[n * 64 + (((0 + quad) ^ (n & 7)) * 8)];
        bf16x8 b1 = *(bf16x8*)&KV[n * 64 + (((4 + quad) ^ (n & 7)) * 8)];
        f32x4 z = {};
        f32x4 t = __builtin_amdgcn_mfma_f32_16x16x32_bf16(aq[0], b0, z, 0, 0, 0);
        sf[nt] = __builtin_amdgcn_mfma_f32_16x16x32_bf16(aq[1], b1, t, 0, 0, 0);
    }
    __syncthreads();

    const ushort* vbase = vp + (size_t)(b * 16 + h) * 16384;
#pragma unroll
    for (int j = 0; j < 8; j++) {
        gld16(&vbase[(w * 8 + j) * 512 + lane * 8], &KV[(w * 8 + j) * 512]);
    }

    const float scale = 0.125f;
    float mx[4] = {-1e30f, -1e30f, -1e30f, -1e30f};
#pragma unroll
    for (int nt = 0; nt < 16; nt++)
#pragma unroll
        for (int reg = 0; reg < 4; reg++) mx[reg] = fmaxf(mx[reg], sf[nt][reg]);
#pragma unroll
    for (int off = 1; off < 16; off <<= 1)
#pragma unroll
        for (int reg = 0; reg < 4; reg++)
            mx[reg] = fmaxf(mx[reg], __shfl_xor(mx[reg], off, 64));
    float sm[4] = {0.f, 0.f, 0.f, 0.f};
#pragma unroll
    for (int nt = 0; nt < 16; nt++)
#pragma unroll
        for (int reg = 0; reg < 4; reg++) {
            float e = __expf((sf[nt][reg] - mx[reg]) * scale);
            sf[nt][reg] = e;
            sm[reg] += e;
        }
#pragma unroll
    for (int off = 1; off < 16; off <<= 1)
#pragma unroll
        for (int reg = 0; reg < 4; reg++)
            sm[reg] += __shfl_xor(sm[reg], off, 64);
    float inv[4];
#pragma unroll
    for (int reg = 0; reg < 4; reg++) inv[reg] = 1.f / sm[reg];

#pragma unroll
    for (int nt = 0; nt < 16; nt++)
#pragma unroll
        for (int reg = 0; reg < 4; reg++) {
            int r = w * 16 + quad * 4 + reg;
            int colc = nt * 2 + (l15 >> 3);
            int addr = r * 256 + ((colc ^ (r & 7)) * 8) + (l15 & 7);
            bf16 hv = __float2bfloat16(sf[nt][reg]);
            P[addr] = *(ushort*)&hv;
        }
    __syncthreads();

    f32x4 of[4] = {};
    int prow = w * 16 + l15;
#pragma unroll
    for (int kk = 0; kk < 8; kk++) {
        bf16x8 ap = *(bf16x8*)&P[prow * 256 + (((kk * 4 + quad) ^ (prow & 7)) * 8)];
#pragma unroll
        for (int dt = 0; dt < 4; dt++) {
            int d = dt * 16 + l15;
            bf16x8 bv = *(bf16x8*)&KV[d * 256 + (((kk * 4 + quad) ^ (d & 7)) * 8)];
            of[dt] = __builtin_amdgcn_mfma_f32_16x16x32_bf16(ap, bv, of[dt], 0, 0, 0);
        }
    }
#pragma unroll
    for (int dt = 0; dt < 4; dt++)
#pragma unroll
        for (int reg = 0; reg < 4; reg++) {
            int r = t0 + w * 16 + quad * 4 + reg;
            y[((size_t)(b * T_ + r) * D_) + h * 64 + dt * 16 + l15] =
                __float2bfloat16(of[dt][reg] * inv[reg]);
        }
}

// ===== stylization -> fp8 a-buf ===========================================
__global__ __launch_bounds__(256) void styl_kernel(const bf16* __restrict__ y,
                                                   const float* __restrict__ g,
                                                   const float* __restrict__ bb,
                                                   const float* __restrict__ embo,
                                                   uchar* __restrict__ a8) {
    int row = blockIdx.x;
    int b = row >> 10;
    int tid = threadIdx.x;
    const ushort* rp = (const ushort*)(y + (size_t)row * D_);
    ushort4 uy = *(const ushort4*)&rp[tid * 4];
    float v0 = bitf((unsigned)uy.x << 16), v1 = bitf((unsigned)uy.y << 16);
    float v2 = bitf((unsigned)uy.z << 16), v3 = bitf((unsigned)uy.w << 16);
    float s = v0 + v1 + v2 + v3;
    float s2 = v0 * v0 + v1 * v1 + v2 * v2 + v3 * v3;
    for (int off = 32; off; off >>= 1) {
        s  += __shfl_down(s,  off, 64);
        s2 += __shfl_down(s2, off, 64);
    }
    __shared__ float ps[4], ps2[4];
    __shared__ float smu, srstd;
    int wid = tid >> 6, lid = tid & 63;
    if (lid == 0) { ps[wid] = s; ps2[wid] = s2; }
    __syncthreads();
    if (tid == 0) {
        float t = ps[0] + ps[1] + ps[2] + ps[3];
        float t2 = ps2[0] + ps2[1] + ps2[2] + ps2[3];
        float m = t / D_;
        float var = t2 / D_ - m * m;
        smu = m; srstd = rsqrtf(var + 1e-5f);
    }
    __syncthreads();
    float mu = smu, rstd = srstd;
    float4 gv = *(const float4*)&g[tid * 4];
    float4 bv = *(const float4*)&bb[tid * 4];
    float4 scv = *(const float4*)&embo[b * 2048 + tid * 4];
    float4 shv = *(const float4*)&embo[b * 2048 + 1024 + tid * 4];
    float n0 = (v0 - mu) * rstd * gv.x + bv.x;
    float n1 = (v1 - mu) * rstd * gv.y + bv.y;
    float n2 = (v2 - mu) * rstd * gv.z + bv.z;
    float n3 = (v3 - mu) * rstd * gv.w + bv.w;
    float h0 = n0 * (1.f + scv.x) + shv.x;
    float h1 = n1 * (1.f + scv.y) + shv.y;
    float h2 = n2 * (1.f + scv.z) + shv.z;
    float h3 = n3 * (1.f + scv.w) + shv.w;
    h0 = h0 / (1.f + __expf(-h0));
    h1 = h1 / (1.f + __expf(-h1));
    h2 = h2 / (1.f + __expf(-h2));
    h3 = h3 / (1.f + __expf(-h3));
    *(int*)&a8[(size_t)row * D_ + tid * 4] = pk4_fp8(h0, h1, h2, h3);
}

extern "C" void kernel_launch(void* const* d_in, const int* in_sizes, int n_in,
                              void* d_out, int out_size, void* d_ws, size_t ws_size,
                              hipStream_t stream) {
    const float* x    = (const float*)d_in[0];
    const float* xf   = (const float*)d_in[1];
    const float* emb  = (const float*)d_in[2];
    const float* ln_g = (const float*)d_in[3];
    const float* ln_b = (const float*)d_in[4];
    const float* cln_g= (const float*)d_in[5];
    const float* cln_b= (const float*)d_in[6];
    const float* Wq   = (const float*)d_in[7];
    const float* bq   = (const float*)d_in[8];
    const float* Wk   = (const float*)d_in[9];
    const float* bk   = (const float*)d_in[10];
    const float* Wv   = (const float*)d_in[11];
    const float* bv   = (const float*)d_in[12];
    const float* sln_g= (const float*)d_in[13];
    const float* sln_b= (const float*)d_in[14];
    const float* Wemb = (const float*)d_in[15];
    const float* bemb = (const float*)d_in[16];
    const float* Wout = (const float*)d_in[17];
    const float* bout = (const float*)d_in[18];
    float* out = (float*)d_out;

    char* wsp = (char*)d_ws;
    const size_t MB = 1024 * 1024;
    uchar* xn8  = (uchar*)(wsp);                  // 8192x1024 fp8   8 MB
    uchar* xfn8 = (uchar*)(wsp + 8 * MB);         // 2048x768  fp8  1.5 MB
    uchar* wq8  = (uchar*)(wsp + 10 * MB);        // 1024x1024 fp8   1 MB
    uchar* wk8  = (uchar*)(wsp + 11 * MB);        // 1024x768  fp8  .75 MB
    uchar* wv8  = (uchar*)(wsp + 12 * MB);        // 1024x768  fp8  .75 MB
    uchar* wo8  = (uchar*)(wsp + 13 * MB);        // 1024x1024 fp8   1 MB
    bf16*  q    = (bf16*)(wsp + 14 * MB);         // 8192x1024 bf16 16 MB
    bf16*  kbuf = (bf16*)(wsp + 30 * MB);         // 2048x1024 bf16  4 MB
    bf16*  vT   = (bf16*)(wsp + 34 * MB);         // pre-swizzled     4 MB
    bf16*  ybuf = (bf16*)(wsp + 38 * MB);         // 8192x1024 bf16 16 MB
    uchar* a8   = (uchar*)(wsp + 54 * MB);        // 8192x1024 fp8   8 MB
    float* embo = (float*)(wsp + 62 * MB);        // 8x2048    f32  64 KB
    float* part = (float*)(wsp + 63 * MB);        // 8x8x2048  f32  512 KB

    prep_kernel<<<11392, 256, 0, stream>>>(x, xf, ln_g, ln_b, cln_g, cln_b,
                                           Wq, Wk, Wv, Wout, emb, Wemb,
                                           xn8, xfn8, wq8, wk8, wv8, wo8, part);

    qkv_gemm<<<1600, 256, 0, stream>>>(xn8, xfn8, wq8, wk8, wv8, bq, bk, bv,
                                       q, kbuf, vT, part, bemb, embo);

    attn_mfma<<<dim3(16, 128), 256, 0, stream>>>(q, kbuf, vT, ybuf);

    styl_kernel<<<B_ * T_, 256, 0, stream>>>(ybuf, sln_g, sln_b, embo, a8);

    out_gemm<<<1024, 256, 0, stream>>>(a8, wo8, bout, x, out);
}